// Round 2
// baseline (1042.910 us; speedup 1.0000x reference)
//
#include <hip/hip_runtime.h>

constexpr int P  = 128;  // input features
constexpr int H  = 64;   // hidden 1
constexpr int H2 = 128;  // hidden 2
constexpr int C  = 2;    // classes

// ---------------- degree / norm ----------------
__global__ void k_init_deg(float* __restrict__ deg, int n){
  int i = blockIdx.x*blockDim.x + threadIdx.x;
  if(i<n) deg[i] = 1.0f;   // self-loop
}

__global__ void k_edge_deg(const int* __restrict__ col, float* __restrict__ deg, int e){
  int i = blockIdx.x*blockDim.x + threadIdx.x;
  if(i<e) atomicAdd(&deg[col[i]], 1.0f);
}

__global__ void k_dinv(float* __restrict__ deg, int n){
  int i = blockIdx.x*blockDim.x + threadIdx.x;
  if(i<n) deg[i] = rsqrtf(deg[i]);   // deg >= 1 always (self-loop)
}

// ---------------- GEMMs (naive, LDS-staged W) ----------------
// t1[n][64] = x[n][128] @ W1[128][64]
__global__ __launch_bounds__(256) void k_gemm1(const float* __restrict__ x,
                                               const float* __restrict__ W,
                                               float* __restrict__ out, int n){
  __shared__ float Ws[P*H];
  for(int i=threadIdx.x;i<P*H;i+=256) Ws[i]=W[i];
  __syncthreads();
  int row = blockIdx.x*4 + (threadIdx.x>>6);
  int col = threadIdx.x & (H-1);
  if(row>=n) return;
  const float* xr = x + (size_t)row*P;
  float acc = 0.f;
  #pragma unroll
  for(int k=0;k<P;k++) acc += xr[k] * Ws[k*H+col];
  out[(size_t)row*H+col] = acc;
}

// g2[n][128] = relu(a2[n][64] @ W2[64][128] + b2)
__global__ __launch_bounds__(256) void k_gemm2(const float* __restrict__ in,
                                               const float* __restrict__ W,
                                               const float* __restrict__ bias,
                                               float* __restrict__ out, int n){
  __shared__ float Ws[H*H2];
  for(int i=threadIdx.x;i<H*H2;i+=256) Ws[i]=W[i];
  __syncthreads();
  int row = blockIdx.x*2 + (threadIdx.x>>7);
  int col = threadIdx.x & (H2-1);
  if(row>=n) return;
  const float* ir = in + (size_t)row*H;
  float acc = bias[col];
  #pragma unroll
  for(int k=0;k<H;k++) acc += ir[k]*Ws[k*H2+col];
  out[(size_t)row*H2+col] = fmaxf(acc, 0.f);
}

// t3[n][2] = g2[n][128] @ W3[128][2]
__global__ __launch_bounds__(256) void k_gemm3(const float* __restrict__ in,
                                               const float* __restrict__ W,
                                               float* __restrict__ out, int n){
  __shared__ float Ws[H2*C];
  for(int i=threadIdx.x;i<H2*C;i+=256) Ws[i]=W[i];
  __syncthreads();
  int rowi = blockIdx.x*blockDim.x + threadIdx.x;
  if(rowi>=n) return;
  const float* ir = in + (size_t)rowi*H2;
  float a0=0.f, a1=0.f;
  #pragma unroll
  for(int k=0;k<H2;k++){ float v=ir[k]; a0 += v*Ws[2*k]; a1 += v*Ws[2*k+1]; }
  out[rowi*2]   = a0;
  out[rowi*2+1] = a1;
}

// ---------------- aggregation: a[col] += dinv[row]*dinv[col]*t[row] ----------------
// init with self-loop term dinv[i]^2 * t[i] (full overwrite -> no memset needed)
template<int F>
__global__ __launch_bounds__(256) void k_agg_init(const float* __restrict__ t,
                                                  const float* __restrict__ dinv,
                                                  float* __restrict__ a, int n){
  int i = blockIdx.x*blockDim.x + threadIdx.x;
  if(i >= n*F) return;
  int node = i / F;
  float d = dinv[node];
  a[i] = d*d*t[i];
}

template<int F>
__global__ __launch_bounds__(256) void k_agg_edge(const int* __restrict__ row,
                                                  const int* __restrict__ col,
                                                  const float* __restrict__ t,
                                                  const float* __restrict__ dinv,
                                                  float* __restrict__ a, long long e){
  long long i = (long long)blockIdx.x*blockDim.x + threadIdx.x;
  if(i >= e*F) return;
  int eg = (int)(i / F), f = (int)(i - (long long)eg*F);  // F=64: one wave == one edge
  int r = row[eg], c = col[eg];
  float nrm = dinv[r]*dinv[c];
  atomicAdd(&a[(size_t)c*F+f], nrm * t[(size_t)r*F+f]);
}

// g = relu(a + b) in place
template<int F>
__global__ void k_bias_relu(float* __restrict__ a, const float* __restrict__ b, int n){
  int i = blockIdx.x*blockDim.x + threadIdx.x;
  if(i >= n*F) return;
  float v = a[i] + b[i & (F-1)];
  a[i] = fmaxf(v, 0.f);
}

// out = log_softmax(a3 + b3) over C=2, write f32
__global__ void k_lsm(const float* __restrict__ a3, const float* __restrict__ b3,
                      float* __restrict__ out, int n){
  int i = blockIdx.x*blockDim.x + threadIdx.x;
  if(i>=n) return;
  float z0 = a3[2*i]   + b3[0];
  float z1 = a3[2*i+1] + b3[1];
  float m = fmaxf(z0,z1);
  float l = m + logf(expf(z0-m)+expf(z1-m));
  out[2*i]   = z0-l;
  out[2*i+1] = z1-l;
}

extern "C" void kernel_launch(void* const* d_in, const int* in_sizes, int n_in,
                              void* d_out, int out_size, void* d_ws, size_t ws_size,
                              hipStream_t stream){
  const float* x  = (const float*)d_in[0];
  const int*   ei = (const int*)  d_in[1];
  const float* W1 = (const float*)d_in[2];
  const float* b1 = (const float*)d_in[3];
  const float* W2 = (const float*)d_in[4];
  const float* b2 = (const float*)d_in[5];
  const float* W3 = (const float*)d_in[6];
  const float* b3 = (const float*)d_in[7];
  float* out = (float*)d_out;

  const int n = in_sizes[0] / P;   // 50000
  const long long e = in_sizes[1] / 2;   // 1600000
  const int* row = ei;             // source
  const int* col = ei + e;         // target

  // workspace layout (f32), lifetime-overlapped; peak = n + 192n floats (~38.6 MB)
  //   S[0..64n)    : a2           (live: agg2 .. gemm2)
  //   S[64n..128n) : a1           (live: agg1 .. agg2)   -- inside g2's future space
  //   S[128n..192n): t1           (live: gemm1 .. agg1)  -- inside g2's future space
  //   S[64n..192n) : g2           (live: gemm2 .. gemm3; a1,t1 dead by then)
  //   S[0..2n)     : t3           (live: gemm3 .. agg3;  a2 dead by then)
  //   S[2n..4n)    : a3           (live: agg3 .. lsm)
  float* ws   = (float*)d_ws;
  float* dinv = ws;
  float* S    = dinv + n;
  float* a2 = S;
  float* a1 = S + (size_t)n*64;
  float* t1 = S + (size_t)n*128;
  float* g2 = S + (size_t)n*64;
  float* t3 = S;
  float* a3 = S + (size_t)n*2;

  const int BT = 256;
  // norm
  k_init_deg<<<(n+BT-1)/BT, BT, 0, stream>>>(dinv, n);
  k_edge_deg<<<(int)((e+BT-1)/BT), BT, 0, stream>>>(col, dinv, (int)e);
  k_dinv    <<<(n+BT-1)/BT, BT, 0, stream>>>(dinv, n);

  // layer 1: transform -> aggregate -> bias+relu
  k_gemm1<<<(n+3)/4, BT, 0, stream>>>(x, W1, t1, n);
  k_agg_init<64><<<(int)(((long long)n*64+BT-1)/BT), BT, 0, stream>>>(t1, dinv, a1, n);
  k_agg_edge<64><<<(int)((e*64+BT-1)/BT), BT, 0, stream>>>(row, col, t1, dinv, a1, e);
  k_bias_relu<64><<<(int)(((long long)n*64+BT-1)/BT), BT, 0, stream>>>(a1, b1, n);

  // layer 2: aggregate FIRST (64 cols, not 128) -> transform+bias+relu
  k_agg_init<64><<<(int)(((long long)n*64+BT-1)/BT), BT, 0, stream>>>(a1, dinv, a2, n);
  k_agg_edge<64><<<(int)((e*64+BT-1)/BT), BT, 0, stream>>>(row, col, a1, dinv, a2, e);
  k_gemm2<<<(n+1)/2, BT, 0, stream>>>(a2, W2, b2, g2, n);

  // layer 3: transform (128->2) -> aggregate 2 cols -> bias+log_softmax
  k_gemm3<<<(n+BT-1)/BT, BT, 0, stream>>>(g2, W3, t3, n);
  k_agg_init<2><<<(int)(((long long)n*2+BT-1)/BT), BT, 0, stream>>>(t3, dinv, a3, n);
  k_agg_edge<2><<<(int)((e*2+BT-1)/BT), BT, 0, stream>>>(row, col, t3, dinv, a3, e);
  k_lsm<<<(n+BT-1)/BT, BT, 0, stream>>>(a3, b3, out, n);
}

// Round 3
// 689.123 us; speedup vs baseline: 1.5134x; 1.5134x over previous
//
#include <hip/hip_runtime.h>

constexpr int P  = 128;  // input features
constexpr int H  = 64;   // hidden 1
constexpr int H2 = 128;  // hidden 2
constexpr int C  = 2;    // classes

// ---------------- CSR build ----------------
__global__ void k_zero(int* __restrict__ p, int n){
  int i = blockIdx.x*blockDim.x + threadIdx.x;
  if(i<n) p[i]=0;
}

__global__ void k_hist(const int* __restrict__ col, int* __restrict__ cnt, int e){
  int i = blockIdx.x*blockDim.x + threadIdx.x;
  if(i<e) atomicAdd(&cnt[col[i]], 1);
}

// dinv[i] = rsqrt(cnt[i] + 1)  (self-loop)
__global__ void k_dinv(const int* __restrict__ cnt, float* __restrict__ dinv, int n){
  int i = blockIdx.x*blockDim.x + threadIdx.x;
  if(i<n) dinv[i] = rsqrtf((float)cnt[i] + 1.0f);
}

// block-level exclusive scan (1024/block)
__global__ __launch_bounds__(1024) void k_scanA(const int* __restrict__ cnt,
                                                int* __restrict__ excl,
                                                int* __restrict__ bsum, int n){
  __shared__ int sm[1024];
  int i = blockIdx.x*1024 + threadIdx.x;
  int v = (i<n)? cnt[i] : 0;
  sm[threadIdx.x] = v; __syncthreads();
  for(int d=1; d<1024; d<<=1){
    int t = (threadIdx.x>=d)? sm[threadIdx.x-d] : 0;
    __syncthreads();
    sm[threadIdx.x] += t;
    __syncthreads();
  }
  if(i<n) excl[i] = sm[threadIdx.x] - v;
  if(threadIdx.x==1023) bsum[blockIdx.x] = sm[1023];
}

__global__ void k_scanB(int* __restrict__ bsum, int nb){
  if(blockIdx.x==0 && threadIdx.x==0){
    int acc=0;
    for(int i=0;i<nb;i++){ int v=bsum[i]; bsum[i]=acc; acc+=v; }
  }
}

__global__ void k_scanC(int* __restrict__ rowptr, const int* __restrict__ bsum,
                        int* __restrict__ cursor, int n, int e){
  int i = blockIdx.x*blockDim.x + threadIdx.x;
  if(i<n){
    int r = rowptr[i] + bsum[i>>10];
    rowptr[i] = r;
    cursor[i] = r;
  }
  if(i==0) rowptr[n] = e;
}

__global__ void k_scatter(const int* __restrict__ row, const int* __restrict__ col,
                          const float* __restrict__ dinv,
                          int* __restrict__ cursor,
                          int* __restrict__ src, float* __restrict__ nrm, int e){
  int i = blockIdx.x*blockDim.x + threadIdx.x;
  if(i>=e) return;
  int r = row[i], c = col[i];
  int pos = atomicAdd(&cursor[c], 1);
  src[pos] = r;
  nrm[pos] = dinv[r]*dinv[c];
}

// ---------------- GEMMs (naive, LDS-staged W) ----------------
__global__ __launch_bounds__(256) void k_gemm1(const float* __restrict__ x,
                                               const float* __restrict__ W,
                                               float* __restrict__ out, int n){
  __shared__ float Ws[P*H];
  for(int i=threadIdx.x;i<P*H;i+=256) Ws[i]=W[i];
  __syncthreads();
  int row = blockIdx.x*4 + (threadIdx.x>>6);
  int col = threadIdx.x & (H-1);
  if(row>=n) return;
  const float* xr = x + (size_t)row*P;
  float acc = 0.f;
  #pragma unroll
  for(int k=0;k<P;k++) acc += xr[k] * Ws[k*H+col];
  out[(size_t)row*H+col] = acc;
}

__global__ __launch_bounds__(256) void k_gemm2(const float* __restrict__ in,
                                               const float* __restrict__ W,
                                               const float* __restrict__ bias,
                                               float* __restrict__ out, int n){
  __shared__ float Ws[H*H2];
  for(int i=threadIdx.x;i<H*H2;i+=256) Ws[i]=W[i];
  __syncthreads();
  int row = blockIdx.x*2 + (threadIdx.x>>7);
  int col = threadIdx.x & (H2-1);
  if(row>=n) return;
  const float* ir = in + (size_t)row*H;
  float acc = bias[col];
  #pragma unroll
  for(int k=0;k<H;k++) acc += ir[k]*Ws[k*H2+col];
  out[(size_t)row*H2+col] = fmaxf(acc, 0.f);
}

__global__ __launch_bounds__(256) void k_gemm3(const float* __restrict__ in,
                                               const float* __restrict__ W,
                                               float* __restrict__ out, int n){
  __shared__ float Ws[H2*C];
  for(int i=threadIdx.x;i<H2*C;i+=256) Ws[i]=W[i];
  __syncthreads();
  int rowi = blockIdx.x*blockDim.x + threadIdx.x;
  if(rowi>=n) return;
  const float* ir = in + (size_t)rowi*H2;
  float a0=0.f, a1=0.f;
  #pragma unroll
  for(int k=0;k<H2;k++){ float v=ir[k]; a0 += v*Ws[2*k]; a1 += v*Ws[2*k+1]; }
  out[rowi*2]   = a0;
  out[rowi*2+1] = a1;
}

// ---------------- pull aggregation: one wave per node, lane = feature ----------------
template<bool BIAS, bool RELU>
__global__ __launch_bounds__(256) void k_pull64(const int* __restrict__ src,
                                                const float* __restrict__ nrm,
                                                const int* __restrict__ rowptr,
                                                const float* __restrict__ t,
                                                const float* __restrict__ dinv,
                                                const float* __restrict__ bias,
                                                float* __restrict__ outp, int n){
  int node = blockIdx.x*4 + (threadIdx.x>>6);
  int lane = threadIdx.x & 63;
  if(node>=n) return;
  float d = dinv[node];
  float acc = d*d*t[(size_t)node*64+lane];   // self-loop
  int beg = rowptr[node], end = rowptr[node+1];
  for(int j=beg;j<end;++j){
    int s = src[j];                           // wave-uniform broadcast load
    acc += nrm[j]*t[(size_t)s*64+lane];       // coalesced 256B gather
  }
  if(BIAS) acc += bias[lane];
  if(RELU) acc = fmaxf(acc, 0.f);
  outp[(size_t)node*64+lane] = acc;
}

// F=2 pull + bias + log_softmax fused; lane-parallel over edges, butterfly reduce
__global__ __launch_bounds__(256) void k_pull2_lsm(const int* __restrict__ src,
                                                   const float* __restrict__ nrm,
                                                   const int* __restrict__ rowptr,
                                                   const float* __restrict__ t3,
                                                   const float* __restrict__ dinv,
                                                   const float* __restrict__ b3,
                                                   float* __restrict__ out, int n){
  int node = blockIdx.x*4 + (threadIdx.x>>6);
  int lane = threadIdx.x & 63;
  if(node>=n) return;
  int beg = rowptr[node], end = rowptr[node+1];
  float p0=0.f, p1=0.f;
  for(int j=beg+lane; j<end; j+=64){
    int s = src[j]; float nm = nrm[j];
    p0 += nm*t3[2*s]; p1 += nm*t3[2*s+1];
  }
  #pragma unroll
  for(int d=32; d; d>>=1){ p0 += __shfl_xor(p0,d); p1 += __shfl_xor(p1,d); }
  if(lane==0){
    float dd = dinv[node];
    float z0 = p0 + dd*dd*t3[2*node]   + b3[0];
    float z1 = p1 + dd*dd*t3[2*node+1] + b3[1];
    float m = fmaxf(z0,z1);
    float l = m + logf(expf(z0-m)+expf(z1-m));
    out[2*node]   = z0-l;
    out[2*node+1] = z1-l;
  }
}

extern "C" void kernel_launch(void* const* d_in, const int* in_sizes, int n_in,
                              void* d_out, int out_size, void* d_ws, size_t ws_size,
                              hipStream_t stream){
  const float* x  = (const float*)d_in[0];
  const int*   ei = (const int*)  d_in[1];
  const float* W1 = (const float*)d_in[2];
  const float* b1 = (const float*)d_in[3];
  const float* W2 = (const float*)d_in[4];
  const float* b2 = (const float*)d_in[5];
  const float* W3 = (const float*)d_in[6];
  const float* b3 = (const float*)d_in[7];
  float* out = (float*)d_out;

  const int n = in_sizes[0] / P;       // 50000
  const int e = in_sizes[1] / 2;       // 1600000
  const int* row = ei;                 // source
  const int* col = ei + e;             // target

  // workspace layout (all 4B elems), lifetime-overlapped:
  //   dinv n | R1 64n | R2 128n | nrm e | cnt n | rowptr n+1 | cursor n | src e | bsum 64
  float* ws   = (float*)d_ws;
  size_t off = 0;
  float* dinv = ws + off; off += n;
  float* R1   = ws + off; off += (size_t)64*n;
  float* R2   = ws + off; off += (size_t)128*n;
  float* nrm  = ws + off; off += e;
  int* cnt    = (int*)(ws + off); off += n;
  int* rowptr = (int*)(ws + off); off += n+1;
  int* cursor = (int*)(ws + off); off += n;
  int* srcA   = (int*)(ws + off); off += e;
  int* bsum   = (int*)(ws + off); off += 64;

  float* t1 = R1;   // gemm1 out         (dead after pull-1)
  float* a1 = R2;   // g1 = relu(agg+b1) (dead after pull-2; R2 reused by g2)
  float* a2 = R1;   // agg of g1         (dead after gemm2)
  float* g2 = R2;   // relu(a2@W2+b2)    (dead after gemm3)
  float* t3 = R1;   // g2@W3, 2n         (dead after pull2_lsm)

  const int BT = 256;
  const int nbScan = (n + 1023)/1024;

  // CSR build
  k_zero   <<<(n+BT-1)/BT, BT, 0, stream>>>(cnt, n);
  k_hist   <<<(e+BT-1)/BT, BT, 0, stream>>>(col, cnt, e);
  k_dinv   <<<(n+BT-1)/BT, BT, 0, stream>>>(cnt, dinv, n);
  k_scanA  <<<nbScan, 1024, 0, stream>>>(cnt, rowptr, bsum, n);
  k_scanB  <<<1, 64, 0, stream>>>(bsum, nbScan);
  k_scanC  <<<(n+BT-1)/BT, BT, 0, stream>>>(rowptr, bsum, cursor, n, e);
  k_scatter<<<(e+BT-1)/BT, BT, 0, stream>>>(row, col, dinv, cursor, srcA, nrm, e);

  // layer 1: transform -> pull-aggregate (+bias+relu fused)
  k_gemm1<<<(n+3)/4, BT, 0, stream>>>(x, W1, t1, n);
  k_pull64<true,true><<<(n+3)/4, BT, 0, stream>>>(srcA, nrm, rowptr, t1, dinv, b1, a1, n);

  // layer 2: pull-aggregate FIRST (64 cols) -> transform+bias+relu
  k_pull64<false,false><<<(n+3)/4, BT, 0, stream>>>(srcA, nrm, rowptr, a1, dinv, nullptr, a2, n);
  k_gemm2<<<(n+1)/2, BT, 0, stream>>>(a2, W2, b2, g2, n);

  // layer 3: transform (128->2) -> pull-aggregate 2 cols + bias + log_softmax fused
  k_gemm3<<<(n+BT-1)/BT, BT, 0, stream>>>(g2, W3, t3, n);
  k_pull2_lsm<<<(n+3)/4, BT, 0, stream>>>(srcA, nrm, rowptr, t3, dinv, b3, out, n);
}

// Round 4
// 533.681 us; speedup vs baseline: 1.9542x; 1.2913x over previous
//
#include <hip/hip_runtime.h>

constexpr int P  = 128;  // input features
constexpr int H  = 64;   // hidden 1
constexpr int H2 = 128;  // hidden 2
constexpr int C  = 2;    // classes

// ---------------- CSR build ----------------
__global__ void k_zero(int* __restrict__ p, int n){
  int i = blockIdx.x*blockDim.x + threadIdx.x;
  if(i<n) p[i]=0;
}

__global__ void k_hist(const int* __restrict__ col, int* __restrict__ cnt, int e){
  int i = blockIdx.x*blockDim.x + threadIdx.x;
  if(i<e) atomicAdd(&cnt[col[i]], 1);
}

// dinv[i] = rsqrt(cnt[i] + 1)  (self-loop)
__global__ void k_dinv(const int* __restrict__ cnt, float* __restrict__ dinv, int n){
  int i = blockIdx.x*blockDim.x + threadIdx.x;
  if(i<n) dinv[i] = rsqrtf((float)cnt[i] + 1.0f);
}

// block-level exclusive scan (1024/block)
__global__ __launch_bounds__(1024) void k_scanA(const int* __restrict__ cnt,
                                                int* __restrict__ excl,
                                                int* __restrict__ bsum, int n){
  __shared__ int sm[1024];
  int i = blockIdx.x*1024 + threadIdx.x;
  int v = (i<n)? cnt[i] : 0;
  sm[threadIdx.x] = v; __syncthreads();
  for(int d=1; d<1024; d<<=1){
    int t = (threadIdx.x>=d)? sm[threadIdx.x-d] : 0;
    __syncthreads();
    sm[threadIdx.x] += t;
    __syncthreads();
  }
  if(i<n) excl[i] = sm[threadIdx.x] - v;
  if(threadIdx.x==1023) bsum[blockIdx.x] = sm[1023];
}

// one-wave exclusive scan over block sums (nb <= 64)
__global__ void k_scanB(int* __restrict__ bsum, int nb){
  int lane = threadIdx.x & 63;
  int v = (lane<nb)? bsum[lane] : 0;
  int s = v;
  #pragma unroll
  for(int d=1; d<64; d<<=1){
    int u = __shfl_up(s, d);
    if(lane>=d) s += u;
  }
  if(lane<nb) bsum[lane] = s - v;   // exclusive
}

__global__ void k_scanC(int* __restrict__ rowptr, const int* __restrict__ bsum,
                        int* __restrict__ cursor, int n, int e){
  int i = blockIdx.x*blockDim.x + threadIdx.x;
  if(i<n){
    int r = rowptr[i] + bsum[i>>10];
    rowptr[i] = r;
    cursor[i] = r;
  }
  if(i==0) rowptr[n] = e;
}

__global__ void k_scatter(const int* __restrict__ row, const int* __restrict__ col,
                          const float* __restrict__ dinv,
                          int* __restrict__ cursor,
                          int* __restrict__ src, float* __restrict__ nrm, int e){
  int i = blockIdx.x*blockDim.x + threadIdx.x;
  if(i>=e) return;
  int r = row[i], c = col[i];
  int pos = atomicAdd(&cursor[c], 1);
  src[pos] = r;
  nrm[pos] = dinv[r]*dinv[c];
}

// ---------------- GEMMs (naive, LDS-staged W) ----------------
__global__ __launch_bounds__(256) void k_gemm1(const float* __restrict__ x,
                                               const float* __restrict__ W,
                                               float* __restrict__ out, int n){
  __shared__ float Ws[P*H];
  for(int i=threadIdx.x;i<P*H;i+=256) Ws[i]=W[i];
  __syncthreads();
  int row = blockIdx.x*4 + (threadIdx.x>>6);
  int col = threadIdx.x & (H-1);
  if(row>=n) return;
  const float* xr = x + (size_t)row*P;
  float acc = 0.f;
  #pragma unroll
  for(int k=0;k<P;k++) acc += xr[k] * Ws[k*H+col];
  out[(size_t)row*H+col] = acc;
}

__global__ __launch_bounds__(256) void k_gemm2(const float* __restrict__ in,
                                               const float* __restrict__ W,
                                               const float* __restrict__ bias,
                                               float* __restrict__ out, int n){
  __shared__ float Ws[H*H2];
  for(int i=threadIdx.x;i<H*H2;i+=256) Ws[i]=W[i];
  __syncthreads();
  int row = blockIdx.x*2 + (threadIdx.x>>7);
  int col = threadIdx.x & (H2-1);
  if(row>=n) return;
  const float* ir = in + (size_t)row*H;
  float acc = bias[col];
  #pragma unroll
  for(int k=0;k<H;k++) acc += ir[k]*Ws[k*H2+col];
  out[(size_t)row*H2+col] = fmaxf(acc, 0.f);
}

__global__ __launch_bounds__(256) void k_gemm3(const float* __restrict__ in,
                                               const float* __restrict__ W,
                                               float* __restrict__ out, int n){
  __shared__ float Ws[H2*C];
  for(int i=threadIdx.x;i<H2*C;i+=256) Ws[i]=W[i];
  __syncthreads();
  int rowi = blockIdx.x*blockDim.x + threadIdx.x;
  if(rowi>=n) return;
  const float* ir = in + (size_t)rowi*H2;
  float a0=0.f, a1=0.f;
  #pragma unroll
  for(int k=0;k<H2;k++){ float v=ir[k]; a0 += v*Ws[2*k]; a1 += v*Ws[2*k+1]; }
  out[rowi*2]   = a0;
  out[rowi*2+1] = a1;
}

// ---------------- pull aggregation: one wave per node, lane = feature ----------------
// 8-way unrolled edge loop -> 8 independent gathers in flight per wave (MLP).
template<bool BIAS, bool RELU>
__global__ __launch_bounds__(256) void k_pull64(const int* __restrict__ src,
                                                const float* __restrict__ nrm,
                                                const int* __restrict__ rowptr,
                                                const float* __restrict__ t,
                                                const float* __restrict__ dinv,
                                                const float* __restrict__ bias,
                                                float* __restrict__ outp, int n){
  int node = blockIdx.x*4 + (threadIdx.x>>6);
  int lane = threadIdx.x & 63;
  if(node>=n) return;
  float d = dinv[node];
  float a0 = d*d*t[(size_t)node*64+lane];   // self-loop
  float a1=0.f,a2=0.f,a3=0.f,a4=0.f,a5=0.f,a6=0.f,a7=0.f;
  int beg = rowptr[node], end = rowptr[node+1];
  int j = beg;
  for(; j+8<=end; j+=8){
    int s0=src[j+0], s1=src[j+1], s2=src[j+2], s3=src[j+3];
    int s4=src[j+4], s5=src[j+5], s6=src[j+6], s7=src[j+7];
    float m0=nrm[j+0], m1=nrm[j+1], m2=nrm[j+2], m3=nrm[j+3];
    float m4=nrm[j+4], m5=nrm[j+5], m6=nrm[j+6], m7=nrm[j+7];
    float g0=t[(size_t)s0*64+lane], g1=t[(size_t)s1*64+lane];
    float g2=t[(size_t)s2*64+lane], g3=t[(size_t)s3*64+lane];
    float g4=t[(size_t)s4*64+lane], g5=t[(size_t)s5*64+lane];
    float g6=t[(size_t)s6*64+lane], g7=t[(size_t)s7*64+lane];
    a0 += m0*g0; a1 += m1*g1; a2 += m2*g2; a3 += m3*g3;
    a4 += m4*g4; a5 += m5*g5; a6 += m6*g6; a7 += m7*g7;
  }
  for(; j<end; ++j) a0 += nrm[j]*t[(size_t)src[j]*64+lane];
  float acc = ((a0+a1)+(a2+a3)) + ((a4+a5)+(a6+a7));
  if(BIAS) acc += bias[lane];
  if(RELU) acc = fmaxf(acc, 0.f);
  outp[(size_t)node*64+lane] = acc;
}

// F=2 pull + bias + log_softmax fused; lane-parallel over edges, butterfly reduce
__global__ __launch_bounds__(256) void k_pull2_lsm(const int* __restrict__ src,
                                                   const float* __restrict__ nrm,
                                                   const int* __restrict__ rowptr,
                                                   const float* __restrict__ t3,
                                                   const float* __restrict__ dinv,
                                                   const float* __restrict__ b3,
                                                   float* __restrict__ out, int n){
  int node = blockIdx.x*4 + (threadIdx.x>>6);
  int lane = threadIdx.x & 63;
  if(node>=n) return;
  int beg = rowptr[node], end = rowptr[node+1];
  float p0=0.f, p1=0.f, q0=0.f, q1=0.f;
  int j = beg + lane;
  for(; j+64 < end; j += 128){
    int sA = src[j];      float nA = nrm[j];
    int sB = src[j+64];   float nB = nrm[j+64];
    float tA0=t3[2*sA], tA1=t3[2*sA+1], tB0=t3[2*sB], tB1=t3[2*sB+1];
    p0 += nA*tA0; p1 += nA*tA1; q0 += nB*tB0; q1 += nB*tB1;
  }
  if(j < end){ int s = src[j]; float nm = nrm[j]; p0 += nm*t3[2*s]; p1 += nm*t3[2*s+1]; }
  p0 += q0; p1 += q1;
  #pragma unroll
  for(int d=32; d; d>>=1){ p0 += __shfl_xor(p0,d); p1 += __shfl_xor(p1,d); }
  if(lane==0){
    float dd = dinv[node];
    float z0 = p0 + dd*dd*t3[2*node]   + b3[0];
    float z1 = p1 + dd*dd*t3[2*node+1] + b3[1];
    float m = fmaxf(z0,z1);
    float l = m + logf(expf(z0-m)+expf(z1-m));
    out[2*node]   = z0-l;
    out[2*node+1] = z1-l;
  }
}

extern "C" void kernel_launch(void* const* d_in, const int* in_sizes, int n_in,
                              void* d_out, int out_size, void* d_ws, size_t ws_size,
                              hipStream_t stream){
  const float* x  = (const float*)d_in[0];
  const int*   ei = (const int*)  d_in[1];
  const float* W1 = (const float*)d_in[2];
  const float* b1 = (const float*)d_in[3];
  const float* W2 = (const float*)d_in[4];
  const float* b2 = (const float*)d_in[5];
  const float* W3 = (const float*)d_in[6];
  const float* b3 = (const float*)d_in[7];
  float* out = (float*)d_out;

  const int n = in_sizes[0] / P;       // 50000
  const int e = in_sizes[1] / 2;       // 1600000
  const int* row = ei;                 // source
  const int* col = ei + e;             // target

  // workspace layout (all 4B elems), lifetime-overlapped:
  float* ws   = (float*)d_ws;
  size_t off = 0;
  float* dinv = ws + off; off += n;
  float* R1   = ws + off; off += (size_t)64*n;
  float* R2   = ws + off; off += (size_t)128*n;
  float* nrm  = ws + off; off += e;
  int* cnt    = (int*)(ws + off); off += n;
  int* rowptr = (int*)(ws + off); off += n+1;
  int* cursor = (int*)(ws + off); off += n;
  int* srcA   = (int*)(ws + off); off += e;
  int* bsum   = (int*)(ws + off); off += 64;

  float* t1 = R1;   // gemm1 out         (dead after pull-1)
  float* a1 = R2;   // g1 = relu(agg+b1) (dead after pull-2; R2 reused by g2)
  float* a2 = R1;   // agg of g1         (dead after gemm2)
  float* g2 = R2;   // relu(a2@W2+b2)    (dead after gemm3)
  float* t3 = R1;   // g2@W3, 2n         (dead after pull2_lsm)

  const int BT = 256;
  const int nbScan = (n + 1023)/1024;

  // CSR build
  k_zero   <<<(n+BT-1)/BT, BT, 0, stream>>>(cnt, n);
  k_hist   <<<(e+BT-1)/BT, BT, 0, stream>>>(col, cnt, e);
  k_dinv   <<<(n+BT-1)/BT, BT, 0, stream>>>(cnt, dinv, n);
  k_scanA  <<<nbScan, 1024, 0, stream>>>(cnt, rowptr, bsum, n);
  k_scanB  <<<1, 64, 0, stream>>>(bsum, nbScan);
  k_scanC  <<<(n+BT-1)/BT, BT, 0, stream>>>(rowptr, bsum, cursor, n, e);
  k_scatter<<<(e+BT-1)/BT, BT, 0, stream>>>(row, col, dinv, cursor, srcA, nrm, e);

  // layer 1: transform -> pull-aggregate (+bias+relu fused)
  k_gemm1<<<(n+3)/4, BT, 0, stream>>>(x, W1, t1, n);
  k_pull64<true,true><<<(n+3)/4, BT, 0, stream>>>(srcA, nrm, rowptr, t1, dinv, b1, a1, n);

  // layer 2: pull-aggregate FIRST (64 cols) -> transform+bias+relu
  k_pull64<false,false><<<(n+3)/4, BT, 0, stream>>>(srcA, nrm, rowptr, a1, dinv, nullptr, a2, n);
  k_gemm2<<<(n+1)/2, BT, 0, stream>>>(a2, W2, b2, g2, n);

  // layer 3: transform (128->2) -> pull-aggregate 2 cols + bias + log_softmax fused
  k_gemm3<<<(n+BT-1)/BT, BT, 0, stream>>>(g2, W3, t3, n);
  k_pull2_lsm<<<(n+3)/4, BT, 0, stream>>>(srcA, nrm, rowptr, t3, dinv, b3, out, n);
}

// Round 5
// 475.112 us; speedup vs baseline: 2.1951x; 1.1233x over previous
//
#include <hip/hip_runtime.h>

constexpr int P  = 128;  // input features
constexpr int H  = 64;   // hidden 1
constexpr int H2 = 128;  // hidden 2
constexpr int C  = 2;    // classes

// ---------------- CSR build ----------------
__global__ void k_zero(int* __restrict__ p, int n){
  int i = blockIdx.x*blockDim.x + threadIdx.x;
  if(i<n) p[i]=0;
}

__global__ void k_hist(const int* __restrict__ col, int* __restrict__ cnt, int e){
  int i = blockIdx.x*blockDim.x + threadIdx.x;
  if(i<e) atomicAdd(&cnt[col[i]], 1);
}

// dinv[i] = rsqrt(cnt[i] + 1)  (self-loop)
__global__ void k_dinv(const int* __restrict__ cnt, float* __restrict__ dinv, int n){
  int i = blockIdx.x*blockDim.x + threadIdx.x;
  if(i<n) dinv[i] = rsqrtf((float)cnt[i] + 1.0f);
}

// block-level exclusive scan (1024/block)
__global__ __launch_bounds__(1024) void k_scanA(const int* __restrict__ cnt,
                                                int* __restrict__ excl,
                                                int* __restrict__ bsum, int n){
  __shared__ int sm[1024];
  int i = blockIdx.x*1024 + threadIdx.x;
  int v = (i<n)? cnt[i] : 0;
  sm[threadIdx.x] = v; __syncthreads();
  for(int d=1; d<1024; d<<=1){
    int t = (threadIdx.x>=d)? sm[threadIdx.x-d] : 0;
    __syncthreads();
    sm[threadIdx.x] += t;
    __syncthreads();
  }
  if(i<n) excl[i] = sm[threadIdx.x] - v;
  if(threadIdx.x==1023) bsum[blockIdx.x] = sm[1023];
}

// one-wave exclusive scan over block sums (nb <= 64)
__global__ void k_scanB(int* __restrict__ bsum, int nb){
  int lane = threadIdx.x & 63;
  int v = (lane<nb)? bsum[lane] : 0;
  int s = v;
  #pragma unroll
  for(int d=1; d<64; d<<=1){
    int u = __shfl_up(s, d);
    if(lane>=d) s += u;
  }
  if(lane<nb) bsum[lane] = s - v;   // exclusive
}

__global__ void k_scanC(int* __restrict__ rowptr, const int* __restrict__ bsum,
                        int* __restrict__ cursor, int n, int e){
  int i = blockIdx.x*blockDim.x + threadIdx.x;
  if(i<n){
    int r = rowptr[i] + bsum[i>>10];
    rowptr[i] = r;
    cursor[i] = r;
  }
  if(i==0) rowptr[n] = e;
}

// only src is scattered now (norm is factored into dinv row/col scaling)
__global__ void k_scatter(const int* __restrict__ row, const int* __restrict__ col,
                          int* __restrict__ cursor, int* __restrict__ src, int e){
  int i = blockIdx.x*blockDim.x + threadIdx.x;
  if(i>=e) return;
  int pos = atomicAdd(&cursor[col[i]], 1);
  src[pos] = row[i];
}

// ---------------- GEMMs (register-blocked: 4 rows/thread) ----------------
// u1[r][c] = dinv[r] * sum_k x[r][k]*W1[k][c]     (16 rows per block)
__global__ __launch_bounds__(256) void k_gemm1(const float* __restrict__ x,
                                               const float* __restrict__ W,
                                               const float* __restrict__ dinv,
                                               float* __restrict__ out, int n){
  __shared__ float Ws[P*H];
  for(int i=threadIdx.x;i<P*H;i+=256) Ws[i]=W[i];
  __syncthreads();
  int col = threadIdx.x & 63;
  int r0 = (blockIdx.x*4 + (threadIdx.x>>6))*4;
  if(r0>=n) return;
  const float* xr = x + (size_t)r0*P;
  if(r0+4<=n){
    float a0=0.f,a1=0.f,a2=0.f,a3=0.f;
    #pragma unroll 4
    for(int k=0;k<P;k++){
      float w = Ws[k*H+col];
      a0 += xr[k      ]*w;
      a1 += xr[P+k    ]*w;
      a2 += xr[2*P+k  ]*w;
      a3 += xr[3*P+k  ]*w;
    }
    out[(size_t)(r0+0)*H+col] = dinv[r0+0]*a0;
    out[(size_t)(r0+1)*H+col] = dinv[r0+1]*a1;
    out[(size_t)(r0+2)*H+col] = dinv[r0+2]*a2;
    out[(size_t)(r0+3)*H+col] = dinv[r0+3]*a3;
  } else {
    for(int i=0;i<4 && r0+i<n;i++){
      float a=0.f;
      for(int k=0;k<P;k++) a += xr[(size_t)i*P+k]*Ws[k*H+col];
      out[(size_t)(r0+i)*H+col] = dinv[r0+i]*a;
    }
  }
}

// g2[r][c] = relu(sum_k a2[r][k]*W2[k][c] + b2[c])   (8 rows per block)
__global__ __launch_bounds__(256) void k_gemm2(const float* __restrict__ in,
                                               const float* __restrict__ W,
                                               const float* __restrict__ bias,
                                               float* __restrict__ out, int n){
  __shared__ float Ws[H*H2];
  for(int i=threadIdx.x;i<H*H2;i+=256) Ws[i]=W[i];
  __syncthreads();
  int col = threadIdx.x & 127;
  int r0 = (blockIdx.x*2 + (threadIdx.x>>7))*4;
  if(r0>=n) return;
  float b = bias[col];
  const float* ir = in + (size_t)r0*H;
  if(r0+4<=n){
    float a0=0.f,a1=0.f,a2=0.f,a3=0.f;
    #pragma unroll 4
    for(int k=0;k<H;k++){
      float w = Ws[k*H2+col];
      a0 += ir[k      ]*w;
      a1 += ir[H+k    ]*w;
      a2 += ir[2*H+k  ]*w;
      a3 += ir[3*H+k  ]*w;
    }
    out[(size_t)(r0+0)*H2+col] = fmaxf(a0+b, 0.f);
    out[(size_t)(r0+1)*H2+col] = fmaxf(a1+b, 0.f);
    out[(size_t)(r0+2)*H2+col] = fmaxf(a2+b, 0.f);
    out[(size_t)(r0+3)*H2+col] = fmaxf(a3+b, 0.f);
  } else {
    for(int i=0;i<4 && r0+i<n;i++){
      float a=0.f;
      for(int k=0;k<H;k++) a += ir[(size_t)i*H+k]*Ws[k*H2+col];
      out[(size_t)(r0+i)*H2+col] = fmaxf(a+b, 0.f);
    }
  }
}

// u3[r][c] = dinv[r] * sum_k g2[r][k]*W3[k][c]   (c in {0,1})
__global__ __launch_bounds__(256) void k_gemm3(const float* __restrict__ in,
                                               const float* __restrict__ W,
                                               const float* __restrict__ dinv,
                                               float* __restrict__ out, int n){
  __shared__ float Ws[H2*C];
  for(int i=threadIdx.x;i<H2*C;i+=256) Ws[i]=W[i];
  __syncthreads();
  int rowi = blockIdx.x*blockDim.x + threadIdx.x;
  if(rowi>=n) return;
  const float* ir = in + (size_t)rowi*H2;
  float a0=0.f, a1=0.f;
  #pragma unroll
  for(int k=0;k<H2;k++){ float v=ir[k]; a0 += v*Ws[2*k]; a1 += v*Ws[2*k+1]; }
  float d = dinv[rowi];
  out[rowi*2]   = d*a0;
  out[rowi*2+1] = d*a1;
}

// ---------------- pull aggregation: one wave per node, lane = feature ----------------
// unweighted gather-sum of pre-scaled rows u; 16 gathers in flight.
// MODE 1: out = dinv * relu(dinv*acc + bias)   (layer-1 epilogue, pre-scaled for layer 2)
// MODE 2: out = dinv * acc                     (layer-2 aggregate)
template<int MODE>
__global__ __launch_bounds__(256) void k_pull64(const int* __restrict__ src,
                                                const int* __restrict__ rowptr,
                                                const float* __restrict__ t,
                                                const float* __restrict__ dinv,
                                                const float* __restrict__ bias,
                                                float* __restrict__ outp, int n){
  int node = blockIdx.x*4 + (threadIdx.x>>6);
  int lane = threadIdx.x & 63;
  if(node>=n) return;
  const size_t NL = (size_t)node*64 + lane;
  float a[8];
  a[0] = t[NL];   // self-loop term u[node]
  #pragma unroll
  for(int u=1;u<8;u++) a[u]=0.f;
  int beg = rowptr[node], end = rowptr[node+1];
  int j = beg;
  for(; j+16<=end; j+=16){
    int s[16];
    #pragma unroll
    for(int u=0;u<16;u++) s[u] = src[j+u];
    float g[16];
    #pragma unroll
    for(int u=0;u<16;u++) g[u] = t[(size_t)s[u]*64+lane];
    #pragma unroll
    for(int u=0;u<16;u++) a[u&7] += g[u];
  }
  for(; j+4<=end; j+=4){
    int s0=src[j], s1=src[j+1], s2=src[j+2], s3=src[j+3];
    a[0] += t[(size_t)s0*64+lane];
    a[1] += t[(size_t)s1*64+lane];
    a[2] += t[(size_t)s2*64+lane];
    a[3] += t[(size_t)s3*64+lane];
  }
  for(; j<end; ++j) a[0] += t[(size_t)src[j]*64+lane];
  float acc = ((a[0]+a[1])+(a[2]+a[3])) + ((a[4]+a[5])+(a[6]+a[7]));
  float d = dinv[node];
  if(MODE==1){
    float h = fmaxf(d*acc + bias[lane], 0.f);
    outp[NL] = d*h;
  } else {
    outp[NL] = d*acc;
  }
}

// F=2 pull + bias + log_softmax fused; lane-parallel over edges, butterfly reduce
__global__ __launch_bounds__(256) void k_pull2_lsm(const int* __restrict__ src,
                                                   const int* __restrict__ rowptr,
                                                   const float* __restrict__ u3,
                                                   const float* __restrict__ dinv,
                                                   const float* __restrict__ b3,
                                                   float* __restrict__ out, int n){
  int node = blockIdx.x*4 + (threadIdx.x>>6);
  int lane = threadIdx.x & 63;
  if(node>=n) return;
  const float2* u = (const float2*)u3;
  int beg = rowptr[node], end = rowptr[node+1];
  float p0=0.f, p1=0.f, q0=0.f, q1=0.f;
  int j = beg + lane;
  for(; j+64 < end; j += 128){
    float2 A = u[src[j]];
    float2 B = u[src[j+64]];
    p0 += A.x; p1 += A.y; q0 += B.x; q1 += B.y;
  }
  if(j < end){ float2 A = u[src[j]]; p0 += A.x; p1 += A.y; }
  p0 += q0; p1 += q1;
  #pragma unroll
  for(int d=32; d; d>>=1){ p0 += __shfl_xor(p0,d); p1 += __shfl_xor(p1,d); }
  if(lane==0){
    float d = dinv[node];
    float2 self = u[node];
    float z0 = d*(p0 + self.x) + b3[0];
    float z1 = d*(p1 + self.y) + b3[1];
    float m = fmaxf(z0,z1);
    float l = m + logf(expf(z0-m)+expf(z1-m));
    out[2*node]   = z0-l;
    out[2*node+1] = z1-l;
  }
}

extern "C" void kernel_launch(void* const* d_in, const int* in_sizes, int n_in,
                              void* d_out, int out_size, void* d_ws, size_t ws_size,
                              hipStream_t stream){
  const float* x  = (const float*)d_in[0];
  const int*   ei = (const int*)  d_in[1];
  const float* W1 = (const float*)d_in[2];
  const float* b1 = (const float*)d_in[3];
  const float* W2 = (const float*)d_in[4];
  const float* b2 = (const float*)d_in[5];
  const float* W3 = (const float*)d_in[6];
  const float* b3 = (const float*)d_in[7];
  float* out = (float*)d_out;

  const int n = in_sizes[0] / P;       // 50000
  const int e = in_sizes[1] / 2;       // 1600000
  const int* row = ei;                 // source
  const int* col = ei + e;             // target

  // workspace layout (all 4B elems), lifetime-overlapped:
  float* ws   = (float*)d_ws;
  size_t off = 0;
  float* dinv = ws + off; off += n;
  float* R1   = ws + off; off += (size_t)64*n;
  float* R2   = ws + off; off += (size_t)128*n;
  int* cnt    = (int*)(ws + off); off += n;
  int* rowptr = (int*)(ws + off); off += n+1;
  int* cursor = (int*)(ws + off); off += n;
  int* srcA   = (int*)(ws + off); off += e;
  int* bsum   = (int*)(ws + off); off += 64;

  float* u1  = R1;   // dinv . (x@W1)          (dead after pull-1)
  float* g1s = R2;   // dinv . relu(layer1)    (dead after pull-2; R2 reused by g2)
  float* a2  = R1;   // layer-2 aggregate      (dead after gemm2)
  float* g2  = R2;   // relu(a2@W2+b2)         (dead after gemm3)
  float* u3  = R1;   // dinv . (g2@W3), 2n     (dead after pull2_lsm)

  const int BT = 256;
  const int nbScan = (n + 1023)/1024;

  // CSR build
  k_zero   <<<(n+BT-1)/BT, BT, 0, stream>>>(cnt, n);
  k_hist   <<<(e+BT-1)/BT, BT, 0, stream>>>(col, cnt, e);
  k_dinv   <<<(n+BT-1)/BT, BT, 0, stream>>>(cnt, dinv, n);
  k_scanA  <<<nbScan, 1024, 0, stream>>>(cnt, rowptr, bsum, n);
  k_scanB  <<<1, 64, 0, stream>>>(bsum, nbScan);
  k_scanC  <<<(n+BT-1)/BT, BT, 0, stream>>>(rowptr, bsum, cursor, n, e);
  k_scatter<<<(e+BT-1)/BT, BT, 0, stream>>>(row, col, cursor, srcA, e);

  // layer 1: transform (+dinv prescale) -> gather-sum -> epilogue (+dinv postscale, prescale for L2)
  k_gemm1<<<(n+15)/16, BT, 0, stream>>>(x, W1, dinv, u1, n);
  k_pull64<1><<<(n+3)/4, BT, 0, stream>>>(srcA, rowptr, u1, dinv, b1, g1s, n);

  // layer 2: gather-sum FIRST (64 cols) -> transform+bias+relu
  k_pull64<2><<<(n+3)/4, BT, 0, stream>>>(srcA, rowptr, g1s, dinv, nullptr, a2, n);
  k_gemm2<<<(n+7)/8, BT, 0, stream>>>(a2, W2, b2, g2, n);

  // layer 3: transform (128->2, +dinv prescale) -> gather-sum + bias + log_softmax fused
  k_gemm3<<<(n+BT-1)/BT, BT, 0, stream>>>(g2, W3, dinv, u3, n);
  k_pull2_lsm<<<(n+3)/4, BT, 0, stream>>>(srcA, rowptr, u3, dinv, b3, out, n);
}

// Round 6
// 332.978 us; speedup vs baseline: 3.1321x; 1.4269x over previous
//
#include <hip/hip_runtime.h>

constexpr int P  = 128;  // input features
constexpr int H  = 64;   // hidden 1
constexpr int H2 = 128;  // hidden 2
constexpr int C  = 2;    // classes

constexpr int BW_LOG = 7;        // bucket width = 128 destinations
constexpr int BWID   = 128;
constexpr int NBMAX  = 512;      // max buckets supported (n <= 65536)
constexpr int T1     = 8192;     // edges per partition block
constexpr int CAP2   = 15360;    // k_csr LDS staging capacity (ints)

// ---------------- CSR build (two-level LDS-staged partition) ----------------
__global__ void k_zero(int* __restrict__ p, int n){
  int i = blockIdx.x*blockDim.x + threadIdx.x;
  if(i<n) p[i]=0;
}

// coarse bucket histogram, LDS-reduced
__global__ __launch_bounds__(256) void k_bhist(const int* __restrict__ col,
                                               int* __restrict__ bcnt, int e, int nb){
  __shared__ int h[NBMAX];
  for(int i=threadIdx.x;i<nb;i+=256) h[i]=0;
  __syncthreads();
  int b0 = blockIdx.x*2048;
  #pragma unroll
  for(int u=0;u<8;u++){
    int idx = b0 + u*256 + threadIdx.x;
    if(idx<e) atomicAdd(&h[col[idx]>>BW_LOG], 1);
  }
  __syncthreads();
  for(int i=threadIdx.x;i<nb;i+=256) if(h[i]) atomicAdd(&bcnt[i], h[i]);
}

// scan bucket counts -> bstart, bcursor
__global__ __launch_bounds__(NBMAX) void k_bscan(const int* __restrict__ bcnt,
                                                 int* __restrict__ bstart,
                                                 int* __restrict__ bcursor, int nb){
  __shared__ int sm[NBMAX];
  int t = threadIdx.x;
  int v = (t<nb)? bcnt[t] : 0;
  sm[t]=v; __syncthreads();
  for(int d=1; d<NBMAX; d<<=1){
    int u = (t>=d)? sm[t-d] : 0;
    __syncthreads();
    sm[t]+=u;
    __syncthreads();
  }
  if(t<nb){ int s = sm[t]-v; bstart[t]=s; bcursor[t]=s; }
}

// partition edges into bucket-contiguous packed pairs (coalesced run writes)
__global__ __launch_bounds__(1024) void k_part(const int* __restrict__ row,
                                               const int* __restrict__ col,
                                               int* __restrict__ bcursor,
                                               unsigned* __restrict__ pairs, int e, int nb){
  __shared__ unsigned stage[T1];
  __shared__ int hist[NBMAX];
  __shared__ int base[NBMAX];
  __shared__ int gpos[NBMAX];
  int tid = threadIdx.x;
  int e0 = blockIdx.x*T1;
  int cnt = min(T1, e-e0);
  for(int i=tid;i<nb;i+=1024) hist[i]=0;
  __syncthreads();
  int myb[8]; int myrank[8]; unsigned mypack[8];
  #pragma unroll
  for(int u=0;u<8;u++){
    int idx = u*1024 + tid;
    if(idx<cnt){
      int c = col[e0+idx], r = row[e0+idx];
      int b = c>>BW_LOG;
      myb[u] = b;
      mypack[u] = ((unsigned)r<<BW_LOG) | (unsigned)(c & (BWID-1));
      myrank[u] = atomicAdd(&hist[b], 1);
    } else myb[u] = -1;
  }
  __syncthreads();
  // inclusive scan of hist into base (first NBMAX threads)
  if(tid<NBMAX) base[tid] = (tid<nb)? hist[tid] : 0;
  __syncthreads();
  for(int d=1; d<NBMAX; d<<=1){
    int u2 = 0;
    if(tid<NBMAX && tid>=d) u2 = base[tid-d];
    __syncthreads();
    if(tid<NBMAX) base[tid] += u2;
    __syncthreads();
  }
  if(tid<nb){
    int ex = base[tid] - hist[tid];       // exclusive
    base[tid] = ex;
    gpos[tid] = atomicAdd(&bcursor[tid], hist[tid]);
  }
  __syncthreads();
  #pragma unroll
  for(int u=0;u<8;u++){
    if(myb[u]>=0) stage[ base[myb[u]] + myrank[u] ] = mypack[u];
  }
  __syncthreads();
  // coalesced run write-out: wave w handles buckets w, w+16, ...
  int wave = tid>>6, lane = tid&63;
  for(int b=wave; b<nb; b+=16){
    int len = hist[b], lo = base[b], go = gpos[b];
    for(int k=lane; k<len; k+=64) pairs[go+k] = stage[lo+k];
  }
}

// per-bucket fine CSR: LDS histogram + scan + scatter, coalesced write; emits rowptr/dinv
__global__ __launch_bounds__(256) void k_csr(const unsigned* __restrict__ pairs,
                                             const int* __restrict__ bstart,
                                             const int* __restrict__ bcnt,
                                             int* __restrict__ srcA,
                                             int* __restrict__ rowptr,
                                             float* __restrict__ dinv,
                                             int n, int e){
  __shared__ int hist[BWID];
  __shared__ int base[BWID];
  __shared__ int cur[BWID];
  __shared__ int stageS[CAP2];
  int b = blockIdx.x, tid = threadIdx.x;
  int lo = bstart[b], cnt = bcnt[b];
  if(tid<BWID) hist[tid]=0;
  __syncthreads();
  for(int i=tid;i<cnt;i+=256) atomicAdd(&hist[pairs[lo+i] & (BWID-1)], 1);
  __syncthreads();
  if(tid<BWID) base[tid] = hist[tid];
  __syncthreads();
  for(int d=1; d<BWID; d<<=1){
    int u = 0;
    if(tid<BWID && tid>=d) u = base[tid-d];
    __syncthreads();
    if(tid<BWID) base[tid] += u;
    __syncthreads();
  }
  if(tid<BWID){
    int ex = base[tid] - hist[tid];
    base[tid] = ex;
    cur[tid] = ex;
    int node = (b<<BW_LOG) + tid;
    if(node<n){
      rowptr[node] = lo + ex;
      dinv[node]   = rsqrtf((float)hist[tid] + 1.0f);
    }
  }
  if(b==0 && tid==0) rowptr[n] = e;
  __syncthreads();
  if(cnt<=CAP2){
    for(int i=tid;i<cnt;i+=256){
      unsigned p = pairs[lo+i];
      int pos = atomicAdd(&cur[p & (BWID-1)], 1);
      stageS[pos] = (int)(p>>BW_LOG);
    }
    __syncthreads();
    for(int i=tid;i<cnt;i+=256) srcA[lo+i] = stageS[i];
  } else {
    // pathological-skew fallback: direct (bucket-local, L2-resident) scatter
    for(int i=tid;i<cnt;i+=256){
      unsigned p = pairs[lo+i];
      int pos = atomicAdd(&cur[p & (BWID-1)], 1);
      srcA[lo+pos] = (int)(p>>BW_LOG);
    }
  }
}

// ---------------- GEMMs (register-blocked: 4 rows/thread) ----------------
__global__ __launch_bounds__(256) void k_gemm1(const float* __restrict__ x,
                                               const float* __restrict__ W,
                                               const float* __restrict__ dinv,
                                               float* __restrict__ out, int n){
  __shared__ float Ws[P*H];
  for(int i=threadIdx.x;i<P*H;i+=256) Ws[i]=W[i];
  __syncthreads();
  int col = threadIdx.x & 63;
  int r0 = (blockIdx.x*4 + (threadIdx.x>>6))*4;
  if(r0>=n) return;
  const float* xr = x + (size_t)r0*P;
  if(r0+4<=n){
    float a0=0.f,a1=0.f,a2=0.f,a3=0.f;
    #pragma unroll 4
    for(int k=0;k<P;k++){
      float w = Ws[k*H+col];
      a0 += xr[k      ]*w;
      a1 += xr[P+k    ]*w;
      a2 += xr[2*P+k  ]*w;
      a3 += xr[3*P+k  ]*w;
    }
    out[(size_t)(r0+0)*H+col] = dinv[r0+0]*a0;
    out[(size_t)(r0+1)*H+col] = dinv[r0+1]*a1;
    out[(size_t)(r0+2)*H+col] = dinv[r0+2]*a2;
    out[(size_t)(r0+3)*H+col] = dinv[r0+3]*a3;
  } else {
    for(int i=0;i<4 && r0+i<n;i++){
      float a=0.f;
      for(int k=0;k<P;k++) a += xr[(size_t)i*P+k]*Ws[k*H+col];
      out[(size_t)(r0+i)*H+col] = dinv[r0+i]*a;
    }
  }
}

__global__ __launch_bounds__(256) void k_gemm2(const float* __restrict__ in,
                                               const float* __restrict__ W,
                                               const float* __restrict__ bias,
                                               float* __restrict__ out, int n){
  __shared__ float Ws[H*H2];
  for(int i=threadIdx.x;i<H*H2;i+=256) Ws[i]=W[i];
  __syncthreads();
  int col = threadIdx.x & 127;
  int r0 = (blockIdx.x*2 + (threadIdx.x>>7))*4;
  if(r0>=n) return;
  float b = bias[col];
  const float* ir = in + (size_t)r0*H;
  if(r0+4<=n){
    float a0=0.f,a1=0.f,a2=0.f,a3=0.f;
    #pragma unroll 4
    for(int k=0;k<H;k++){
      float w = Ws[k*H2+col];
      a0 += ir[k      ]*w;
      a1 += ir[H+k    ]*w;
      a2 += ir[2*H+k  ]*w;
      a3 += ir[3*H+k  ]*w;
    }
    out[(size_t)(r0+0)*H2+col] = fmaxf(a0+b, 0.f);
    out[(size_t)(r0+1)*H2+col] = fmaxf(a1+b, 0.f);
    out[(size_t)(r0+2)*H2+col] = fmaxf(a2+b, 0.f);
    out[(size_t)(r0+3)*H2+col] = fmaxf(a3+b, 0.f);
  } else {
    for(int i=0;i<4 && r0+i<n;i++){
      float a=0.f;
      for(int k=0;k<H;k++) a += ir[(size_t)i*H+k]*Ws[k*H2+col];
      out[(size_t)(r0+i)*H2+col] = fmaxf(a+b, 0.f);
    }
  }
}

__global__ __launch_bounds__(256) void k_gemm3(const float* __restrict__ in,
                                               const float* __restrict__ W,
                                               const float* __restrict__ dinv,
                                               float* __restrict__ out, int n){
  __shared__ float Ws[H2*C];
  for(int i=threadIdx.x;i<H2*C;i+=256) Ws[i]=W[i];
  __syncthreads();
  int rowi = blockIdx.x*blockDim.x + threadIdx.x;
  if(rowi>=n) return;
  const float* ir = in + (size_t)rowi*H2;
  float a0=0.f, a1=0.f;
  #pragma unroll
  for(int k=0;k<H2;k++){ float v=ir[k]; a0 += v*Ws[2*k]; a1 += v*Ws[2*k+1]; }
  float d = dinv[rowi];
  out[rowi*2]   = d*a0;
  out[rowi*2+1] = d*a1;
}

// ---------------- pull aggregation: one wave per node, lane = feature ----------------
// unweighted gather-sum of pre-scaled rows u; 16 gathers in flight.
// MODE 1: out = dinv * relu(dinv*acc + bias)   (layer-1 epilogue, pre-scaled for layer 2)
// MODE 2: out = dinv * acc                     (layer-2 aggregate)
template<int MODE>
__global__ __launch_bounds__(256) void k_pull64(const int* __restrict__ src,
                                                const int* __restrict__ rowptr,
                                                const float* __restrict__ t,
                                                const float* __restrict__ dinv,
                                                const float* __restrict__ bias,
                                                float* __restrict__ outp, int n){
  int node = blockIdx.x*4 + (threadIdx.x>>6);
  int lane = threadIdx.x & 63;
  if(node>=n) return;
  const size_t NL = (size_t)node*64 + lane;
  float a[8];
  a[0] = t[NL];   // self-loop term u[node]
  #pragma unroll
  for(int u=1;u<8;u++) a[u]=0.f;
  int beg = rowptr[node], end = rowptr[node+1];
  int j = beg;
  for(; j+16<=end; j+=16){
    int s[16];
    #pragma unroll
    for(int u=0;u<16;u++) s[u] = src[j+u];
    float g[16];
    #pragma unroll
    for(int u=0;u<16;u++) g[u] = t[(size_t)s[u]*64+lane];
    #pragma unroll
    for(int u=0;u<16;u++) a[u&7] += g[u];
  }
  for(; j+4<=end; j+=4){
    int s0=src[j], s1=src[j+1], s2=src[j+2], s3=src[j+3];
    a[0] += t[(size_t)s0*64+lane];
    a[1] += t[(size_t)s1*64+lane];
    a[2] += t[(size_t)s2*64+lane];
    a[3] += t[(size_t)s3*64+lane];
  }
  for(; j<end; ++j) a[0] += t[(size_t)src[j]*64+lane];
  float acc = ((a[0]+a[1])+(a[2]+a[3])) + ((a[4]+a[5])+(a[6]+a[7]));
  float d = dinv[node];
  if(MODE==1){
    float h = fmaxf(d*acc + bias[lane], 0.f);
    outp[NL] = d*h;
  } else {
    outp[NL] = d*acc;
  }
}

// F=2 pull + bias + log_softmax fused; lane-parallel over edges, butterfly reduce
__global__ __launch_bounds__(256) void k_pull2_lsm(const int* __restrict__ src,
                                                   const int* __restrict__ rowptr,
                                                   const float* __restrict__ u3,
                                                   const float* __restrict__ dinv,
                                                   const float* __restrict__ b3,
                                                   float* __restrict__ out, int n){
  int node = blockIdx.x*4 + (threadIdx.x>>6);
  int lane = threadIdx.x & 63;
  if(node>=n) return;
  const float2* u = (const float2*)u3;
  int beg = rowptr[node], end = rowptr[node+1];
  float p0=0.f, p1=0.f, q0=0.f, q1=0.f;
  int j = beg + lane;
  for(; j+64 < end; j += 128){
    float2 A = u[src[j]];
    float2 B = u[src[j+64]];
    p0 += A.x; p1 += A.y; q0 += B.x; q1 += B.y;
  }
  if(j < end){ float2 A = u[src[j]]; p0 += A.x; p1 += A.y; }
  p0 += q0; p1 += q1;
  #pragma unroll
  for(int d=32; d; d>>=1){ p0 += __shfl_xor(p0,d); p1 += __shfl_xor(p1,d); }
  if(lane==0){
    float d = dinv[node];
    float2 self = u[node];
    float z0 = d*(p0 + self.x) + b3[0];
    float z1 = d*(p1 + self.y) + b3[1];
    float m = fmaxf(z0,z1);
    float l = m + logf(expf(z0-m)+expf(z1-m));
    out[2*node]   = z0-l;
    out[2*node+1] = z1-l;
  }
}

extern "C" void kernel_launch(void* const* d_in, const int* in_sizes, int n_in,
                              void* d_out, int out_size, void* d_ws, size_t ws_size,
                              hipStream_t stream){
  const float* x  = (const float*)d_in[0];
  const int*   ei = (const int*)  d_in[1];
  const float* W1 = (const float*)d_in[2];
  const float* b1 = (const float*)d_in[3];
  const float* W2 = (const float*)d_in[4];
  const float* b2 = (const float*)d_in[5];
  const float* W3 = (const float*)d_in[6];
  const float* b3 = (const float*)d_in[7];
  float* out = (float*)d_out;

  const int n = in_sizes[0] / P;       // 50000
  const int e = in_sizes[1] / 2;       // 1600000
  const int* row = ei;                 // source
  const int* col = ei + e;             // target
  const int nb = (n + BWID - 1) >> BW_LOG;   // 391 buckets (requires n <= 65536)

  // workspace layout (all 4B elems), lifetime-overlapped:
  float* ws   = (float*)d_ws;
  size_t off = 0;
  float* dinv = ws + off; off += n;
  float* R1   = ws + off; off += (size_t)64*n;
  float* R2   = ws + off; off += (size_t)128*n;
  int* rowptr = (int*)(ws + off); off += n+1;
  int* srcA   = (int*)(ws + off); off += e;
  int* bcnt   = (int*)(ws + off); off += NBMAX;
  int* bstart = (int*)(ws + off); off += NBMAX;
  int* bcursor= (int*)(ws + off); off += NBMAX;

  unsigned* pairs = (unsigned*)R2;  // e u32s, live only during CSR build (R2 dead then)

  float* u1  = R1;   // dinv . (x@W1)          (dead after pull-1)
  float* g1s = R2;   // dinv . relu(layer1)    (dead after pull-2; R2 reused by g2)
  float* a2  = R1;   // layer-2 aggregate      (dead after gemm2)
  float* g2  = R2;   // relu(a2@W2+b2)         (dead after gemm3)
  float* u3  = R1;   // dinv . (g2@W3), 2n     (dead after pull2_lsm)

  const int BT = 256;

  // CSR build: coarse hist -> scan -> LDS-staged partition -> per-bucket fine CSR
  k_zero <<<(nb+BT-1)/BT, BT, 0, stream>>>(bcnt, nb);
  k_bhist<<<(e+2047)/2048, BT, 0, stream>>>(col, bcnt, e, nb);
  k_bscan<<<1, NBMAX, 0, stream>>>(bcnt, bstart, bcursor, nb);
  k_part <<<(e+T1-1)/T1, 1024, 0, stream>>>(row, col, bcursor, pairs, e, nb);
  k_csr  <<<nb, BT, 0, stream>>>(pairs, bstart, bcnt, srcA, rowptr, dinv, n, e);

  // layer 1: transform (+dinv prescale) -> gather-sum -> epilogue (+dinv postscale, prescale for L2)
  k_gemm1<<<(n+15)/16, BT, 0, stream>>>(x, W1, dinv, u1, n);
  k_pull64<1><<<(n+3)/4, BT, 0, stream>>>(srcA, rowptr, u1, dinv, b1, g1s, n);

  // layer 2: gather-sum FIRST (64 cols) -> transform+bias+relu
  k_pull64<2><<<(n+3)/4, BT, 0, stream>>>(srcA, rowptr, g1s, dinv, nullptr, a2, n);
  k_gemm2<<<(n+7)/8, BT, 0, stream>>>(a2, W2, b2, g2, n);

  // layer 3: transform (128->2, +dinv prescale) -> gather-sum + bias + log_softmax fused
  k_gemm3<<<(n+BT-1)/BT, BT, 0, stream>>>(g2, W3, dinv, u3, n);
  k_pull2_lsm<<<(n+3)/4, BT, 0, stream>>>(srcA, rowptr, u3, dinv, b3, out, n);
}

// Round 7
// 243.915 us; speedup vs baseline: 4.2757x; 1.3651x over previous
//
#include <hip/hip_runtime.h>

constexpr int P  = 128;  // input features
constexpr int H  = 64;   // hidden 1
constexpr int H2 = 128;  // hidden 2
constexpr int C  = 2;    // classes

constexpr int BW_LOG = 7;        // bucket width = 128 destinations
constexpr int BWID   = 128;
constexpr int NBMAX  = 512;      // max buckets supported (n <= 65536)
constexpr int T1     = 8192;     // edges per partition block
constexpr int CAP2   = 15360;    // k_csr LDS staging capacity (ints)

// ---------------- CSR build (two-level LDS-staged partition) ----------------
__global__ void k_zero(int* __restrict__ p, int n){
  int i = blockIdx.x*blockDim.x + threadIdx.x;
  if(i<n) p[i]=0;
}

__global__ __launch_bounds__(256) void k_bhist(const int* __restrict__ col,
                                               int* __restrict__ bcnt, int e, int nb){
  __shared__ int h[NBMAX];
  for(int i=threadIdx.x;i<nb;i+=256) h[i]=0;
  __syncthreads();
  int b0 = blockIdx.x*2048;
  #pragma unroll
  for(int u=0;u<8;u++){
    int idx = b0 + u*256 + threadIdx.x;
    if(idx<e) atomicAdd(&h[col[idx]>>BW_LOG], 1);
  }
  __syncthreads();
  for(int i=threadIdx.x;i<nb;i+=256) if(h[i]) atomicAdd(&bcnt[i], h[i]);
}

__global__ __launch_bounds__(NBMAX) void k_bscan(const int* __restrict__ bcnt,
                                                 int* __restrict__ bstart,
                                                 int* __restrict__ bcursor, int nb){
  __shared__ int sm[NBMAX];
  int t = threadIdx.x;
  int v = (t<nb)? bcnt[t] : 0;
  sm[t]=v; __syncthreads();
  for(int d=1; d<NBMAX; d<<=1){
    int u = (t>=d)? sm[t-d] : 0;
    __syncthreads();
    sm[t]+=u;
    __syncthreads();
  }
  if(t<nb){ int s = sm[t]-v; bstart[t]=s; bcursor[t]=s; }
}

__global__ __launch_bounds__(1024) void k_part(const int* __restrict__ row,
                                               const int* __restrict__ col,
                                               int* __restrict__ bcursor,
                                               unsigned* __restrict__ pairs, int e, int nb){
  __shared__ unsigned stage[T1];
  __shared__ int hist[NBMAX];
  __shared__ int base[NBMAX];
  __shared__ int gpos[NBMAX];
  int tid = threadIdx.x;
  int e0 = blockIdx.x*T1;
  int cnt = min(T1, e-e0);
  for(int i=tid;i<nb;i+=1024) hist[i]=0;
  __syncthreads();
  int myb[8]; int myrank[8]; unsigned mypack[8];
  #pragma unroll
  for(int u=0;u<8;u++){
    int idx = u*1024 + tid;
    if(idx<cnt){
      int c = col[e0+idx], r = row[e0+idx];
      int b = c>>BW_LOG;
      myb[u] = b;
      mypack[u] = ((unsigned)r<<BW_LOG) | (unsigned)(c & (BWID-1));
      myrank[u] = atomicAdd(&hist[b], 1);
    } else myb[u] = -1;
  }
  __syncthreads();
  if(tid<NBMAX) base[tid] = (tid<nb)? hist[tid] : 0;
  __syncthreads();
  for(int d=1; d<NBMAX; d<<=1){
    int u2 = 0;
    if(tid<NBMAX && tid>=d) u2 = base[tid-d];
    __syncthreads();
    if(tid<NBMAX) base[tid] += u2;
    __syncthreads();
  }
  if(tid<nb){
    int ex = base[tid] - hist[tid];
    base[tid] = ex;
    gpos[tid] = atomicAdd(&bcursor[tid], hist[tid]);
  }
  __syncthreads();
  #pragma unroll
  for(int u=0;u<8;u++){
    if(myb[u]>=0) stage[ base[myb[u]] + myrank[u] ] = mypack[u];
  }
  __syncthreads();
  int wave = tid>>6, lane = tid&63;
  for(int b=wave; b<nb; b+=16){
    int len = hist[b], lo = base[b], go = gpos[b];
    for(int k=lane; k<len; k+=64) pairs[go+k] = stage[lo+k];
  }
}

__global__ __launch_bounds__(256) void k_csr(const unsigned* __restrict__ pairs,
                                             const int* __restrict__ bstart,
                                             const int* __restrict__ bcnt,
                                             int* __restrict__ srcA,
                                             int* __restrict__ rowptr,
                                             float* __restrict__ dinv,
                                             int n, int e){
  __shared__ int hist[BWID];
  __shared__ int base[BWID];
  __shared__ int cur[BWID];
  __shared__ int stageS[CAP2];
  int b = blockIdx.x, tid = threadIdx.x;
  int lo = bstart[b], cnt = bcnt[b];
  if(tid<BWID) hist[tid]=0;
  __syncthreads();
  for(int i=tid;i<cnt;i+=256) atomicAdd(&hist[pairs[lo+i] & (BWID-1)], 1);
  __syncthreads();
  if(tid<BWID) base[tid] = hist[tid];
  __syncthreads();
  for(int d=1; d<BWID; d<<=1){
    int u = 0;
    if(tid<BWID && tid>=d) u = base[tid-d];
    __syncthreads();
    if(tid<BWID) base[tid] += u;
    __syncthreads();
  }
  if(tid<BWID){
    int ex = base[tid] - hist[tid];
    base[tid] = ex;
    cur[tid] = ex;
    int node = (b<<BW_LOG) + tid;
    if(node<n){
      rowptr[node] = lo + ex;
      dinv[node]   = rsqrtf((float)hist[tid] + 1.0f);
    }
  }
  if(b==0 && tid==0) rowptr[n] = e;
  __syncthreads();
  if(cnt<=CAP2){
    for(int i=tid;i<cnt;i+=256){
      unsigned p = pairs[lo+i];
      int pos = atomicAdd(&cur[p & (BWID-1)], 1);
      stageS[pos] = (int)(p>>BW_LOG);
    }
    __syncthreads();
    for(int i=tid;i<cnt;i+=256) srcA[lo+i] = stageS[i];
  } else {
    for(int i=tid;i<cnt;i+=256){
      unsigned p = pairs[lo+i];
      int pos = atomicAdd(&cur[p & (BWID-1)], 1);
      srcA[lo+pos] = (int)(p>>BW_LOG);
    }
  }
}

// ---------------- GEMM1: tiled 64x64, k-split LDS staging ----------------
// u1[r][c] = dinv[r] * sum_k x[r][k] * W1[k][c]
__global__ __launch_bounds__(256) void k_gemm1(const float* __restrict__ x,
                                               const float* __restrict__ W,
                                               const float* __restrict__ dinv,
                                               float* __restrict__ out, int n){
  __shared__ float xs[64][68];   // x tile half-k: [r][kk], stride 68 -> bank 4r+kk
  __shared__ float ws[64][64];   // W half-k: [kk][c]
  int tid = threadIdx.x;
  int tx = tid & 15, ty = tid >> 4;
  int r0 = blockIdx.x*64;
  float acc[4][4] = {};
  const float4* x4 = (const float4*)x;
  const float4* W4 = (const float4*)W;
  for(int kh=0; kh<2; ++kh){
    __syncthreads();
    // stage x half: 64 rows x 16 quads
    #pragma unroll
    for(int it=0; it<4; ++it){
      int idx = tid + 256*it;
      int r = idx >> 4, k4 = idx & 15;
      int gr = r0 + r;
      float4 v = (gr<n) ? x4[(size_t)gr*32 + kh*16 + k4] : make_float4(0.f,0.f,0.f,0.f);
      *(float4*)&xs[r][4*k4] = v;
    }
    // stage W half: 64 k x 16 quads
    #pragma unroll
    for(int it=0; it<4; ++it){
      int idx = tid + 256*it;
      int kk = idx >> 4, c4 = idx & 15;
      *(float4*)&ws[kk][4*c4] = W4[(size_t)(kh*64+kk)*16 + c4];
    }
    __syncthreads();
    #pragma unroll 8
    for(int kk=0; kk<64; ++kk){
      float xv0 = xs[4*ty+0][kk];
      float xv1 = xs[4*ty+1][kk];
      float xv2 = xs[4*ty+2][kk];
      float xv3 = xs[4*ty+3][kk];
      float4 wv = *(const float4*)&ws[kk][4*tx];
      acc[0][0] += xv0*wv.x; acc[0][1] += xv0*wv.y; acc[0][2] += xv0*wv.z; acc[0][3] += xv0*wv.w;
      acc[1][0] += xv1*wv.x; acc[1][1] += xv1*wv.y; acc[1][2] += xv1*wv.z; acc[1][3] += xv1*wv.w;
      acc[2][0] += xv2*wv.x; acc[2][1] += xv2*wv.y; acc[2][2] += xv2*wv.z; acc[2][3] += xv2*wv.w;
      acc[3][0] += xv3*wv.x; acc[3][1] += xv3*wv.y; acc[3][2] += xv3*wv.z; acc[3][3] += xv3*wv.w;
    }
  }
  #pragma unroll
  for(int i=0;i<4;i++){
    int gr = r0 + 4*ty + i;
    if(gr<n){
      float d = dinv[gr];
      float4 o = make_float4(acc[i][0]*d, acc[i][1]*d, acc[i][2]*d, acc[i][3]*d);
      *(float4*)&out[(size_t)gr*64 + 4*tx] = o;
    }
  }
}

// ---------------- GEMM2+GEMM3 fused ----------------
// h2 = relu(a2 @ W2 + b2) in registers; u3[r][cls] = dinv[r]*sum_c h2[r][c]*W3[c][cls]
__global__ __launch_bounds__(256) void k_gemm23(const float* __restrict__ a2,
                                                const float* __restrict__ W2,
                                                const float* __restrict__ b2,
                                                const float* __restrict__ W3,
                                                const float* __restrict__ dinv,
                                                float* __restrict__ u3, int n){
  __shared__ float as[64][68];     // a2 tile [r][k]
  __shared__ float ws[64][128];    // W2 [k][c]
  __shared__ float w3s[H2*C];      // W3 [c][cls]
  __shared__ float b2s[H2];
  int tid = threadIdx.x;
  int tx = tid & 15, ty = tid >> 4;
  int r0 = blockIdx.x*64;
  const float4* a4 = (const float4*)a2;
  const float4* W24 = (const float4*)W2;
  // stage a2: 64 rows x 16 quads
  #pragma unroll
  for(int it=0; it<4; ++it){
    int idx = tid + 256*it;
    int r = idx >> 4, k4 = idx & 15;
    int gr = r0 + r;
    float4 v = (gr<n) ? a4[(size_t)gr*16 + k4] : make_float4(0.f,0.f,0.f,0.f);
    *(float4*)&as[r][4*k4] = v;
  }
  // stage W2: 64 k x 32 quads
  #pragma unroll
  for(int it=0; it<8; ++it){
    int idx = tid + 256*it;
    int kk = idx >> 5, c4 = idx & 31;
    *(float4*)&ws[kk][4*c4] = W24[(size_t)kk*32 + c4];
  }
  if(tid < H2*C) w3s[tid] = W3[tid];
  if(tid < H2)   b2s[tid] = b2[tid];
  __syncthreads();
  float acc[4][8] = {};
  #pragma unroll 4
  for(int kk=0; kk<64; ++kk){
    float xv0 = as[4*ty+0][kk];
    float xv1 = as[4*ty+1][kk];
    float xv2 = as[4*ty+2][kk];
    float xv3 = as[4*ty+3][kk];
    float4 wa = *(const float4*)&ws[kk][8*tx];
    float4 wb = *(const float4*)&ws[kk][8*tx+4];
    acc[0][0]+=xv0*wa.x; acc[0][1]+=xv0*wa.y; acc[0][2]+=xv0*wa.z; acc[0][3]+=xv0*wa.w;
    acc[0][4]+=xv0*wb.x; acc[0][5]+=xv0*wb.y; acc[0][6]+=xv0*wb.z; acc[0][7]+=xv0*wb.w;
    acc[1][0]+=xv1*wa.x; acc[1][1]+=xv1*wa.y; acc[1][2]+=xv1*wa.z; acc[1][3]+=xv1*wa.w;
    acc[1][4]+=xv1*wb.x; acc[1][5]+=xv1*wb.y; acc[1][6]+=xv1*wb.z; acc[1][7]+=xv1*wb.w;
    acc[2][0]+=xv2*wa.x; acc[2][1]+=xv2*wa.y; acc[2][2]+=xv2*wa.z; acc[2][3]+=xv2*wa.w;
    acc[2][4]+=xv2*wb.x; acc[2][5]+=xv2*wb.y; acc[2][6]+=xv2*wb.z; acc[2][7]+=xv2*wb.w;
    acc[3][0]+=xv3*wa.x; acc[3][1]+=xv3*wa.y; acc[3][2]+=xv3*wa.z; acc[3][3]+=xv3*wa.w;
    acc[3][4]+=xv3*wb.x; acc[3][5]+=xv3*wb.y; acc[3][6]+=xv3*wb.z; acc[3][7]+=xv3*wb.w;
  }
  // epilogue: relu + fold into W3, reduce over tx (lanes xor 1,2,4,8)
  float p[4][2] = {};
  #pragma unroll
  for(int j=0;j<8;j++){
    int c = 8*tx + j;
    float w30 = w3s[2*c], w31 = w3s[2*c+1], bb = b2s[c];
    #pragma unroll
    for(int i=0;i<4;i++){
      float g = fmaxf(acc[i][j] + bb, 0.f);
      p[i][0] += g*w30;
      p[i][1] += g*w31;
    }
  }
  #pragma unroll
  for(int d=1; d<16; d<<=1){
    #pragma unroll
    for(int i=0;i<4;i++){
      p[i][0] += __shfl_xor(p[i][0], d);
      p[i][1] += __shfl_xor(p[i][1], d);
    }
  }
  if(tx==0){
    #pragma unroll
    for(int i=0;i<4;i++){
      int gr = r0 + 4*ty + i;
      if(gr<n){
        float d = dinv[gr];
        u3[2*gr]   = d*p[i][0];
        u3[2*gr+1] = d*p[i][1];
      }
    }
  }
}

// ---------------- pull aggregation: wave per node, 16 lanes per edge ----------------
// lane = 16*g + l4: g = edge slot (0..3), l4 = feature quad. One dwordx4 gather
// covers 4 features of one edge; 4 edges in flight per instruction group.
// MODE 1: out = dinv * relu(dinv*sum + bias)   MODE 2: out = dinv * sum
template<int MODE>
__global__ __launch_bounds__(256) void k_pull64(const int* __restrict__ src,
                                                const int* __restrict__ rowptr,
                                                const float* __restrict__ t,
                                                const float* __restrict__ dinv,
                                                const float* __restrict__ bias,
                                                float* __restrict__ outp, int n){
  int node = blockIdx.x*4 + (threadIdx.x>>6);
  int lane = threadIdx.x & 63;
  if(node>=n) return;
  int g  = lane >> 4;
  int l4 = lane & 15;
  const float4* t4 = (const float4*)t;
  float4 acc = make_float4(0.f,0.f,0.f,0.f);
  int beg = rowptr[node], end = rowptr[node+1];
  int j = beg;
  for(; j+16<=end; j+=16){
    int s0 = src[j +      g];
    int s1 = src[j + 4  + g];
    int s2 = src[j + 8  + g];
    int s3 = src[j + 12 + g];
    float4 v0 = t4[(size_t)s0*16 + l4];
    float4 v1 = t4[(size_t)s1*16 + l4];
    float4 v2 = t4[(size_t)s2*16 + l4];
    float4 v3 = t4[(size_t)s3*16 + l4];
    acc.x += (v0.x+v1.x) + (v2.x+v3.x);
    acc.y += (v0.y+v1.y) + (v2.y+v3.y);
    acc.z += (v0.z+v1.z) + (v2.z+v3.z);
    acc.w += (v0.w+v1.w) + (v2.w+v3.w);
  }
  for(; j+4<=end; j+=4){
    int s = src[j+g];
    float4 v = t4[(size_t)s*16 + l4];
    acc.x += v.x; acc.y += v.y; acc.z += v.z; acc.w += v.w;
  }
  if(j + g < end){
    int s = src[j+g];
    float4 v = t4[(size_t)s*16 + l4];
    acc.x += v.x; acc.y += v.y; acc.z += v.z; acc.w += v.w;
  }
  // reduce across the 4 edge slots
  acc.x += __shfl_xor(acc.x,16); acc.y += __shfl_xor(acc.y,16);
  acc.z += __shfl_xor(acc.z,16); acc.w += __shfl_xor(acc.w,16);
  acc.x += __shfl_xor(acc.x,32); acc.y += __shfl_xor(acc.y,32);
  acc.z += __shfl_xor(acc.z,32); acc.w += __shfl_xor(acc.w,32);
  if(g==0){
    float4 self = t4[(size_t)node*16 + l4];
    float d = dinv[node];
    float4 o;
    if(MODE==1){
      float4 bq = ((const float4*)bias)[l4];
      o.x = d*fmaxf(d*(acc.x+self.x) + bq.x, 0.f);
      o.y = d*fmaxf(d*(acc.y+self.y) + bq.y, 0.f);
      o.z = d*fmaxf(d*(acc.z+self.z) + bq.z, 0.f);
      o.w = d*fmaxf(d*(acc.w+self.w) + bq.w, 0.f);
    } else {
      o.x = d*(acc.x+self.x);
      o.y = d*(acc.y+self.y);
      o.z = d*(acc.z+self.z);
      o.w = d*(acc.w+self.w);
    }
    ((float4*)outp)[(size_t)node*16 + l4] = o;
  }
}

// F=2 pull + bias + log_softmax fused
__global__ __launch_bounds__(256) void k_pull2_lsm(const int* __restrict__ src,
                                                   const int* __restrict__ rowptr,
                                                   const float* __restrict__ u3,
                                                   const float* __restrict__ dinv,
                                                   const float* __restrict__ b3,
                                                   float* __restrict__ out, int n){
  int node = blockIdx.x*4 + (threadIdx.x>>6);
  int lane = threadIdx.x & 63;
  if(node>=n) return;
  const float2* u = (const float2*)u3;
  int beg = rowptr[node], end = rowptr[node+1];
  float p0=0.f, p1=0.f, q0=0.f, q1=0.f;
  int j = beg + lane;
  for(; j+64 < end; j += 128){
    float2 A = u[src[j]];
    float2 B = u[src[j+64]];
    p0 += A.x; p1 += A.y; q0 += B.x; q1 += B.y;
  }
  if(j < end){ float2 A = u[src[j]]; p0 += A.x; p1 += A.y; }
  p0 += q0; p1 += q1;
  #pragma unroll
  for(int d=32; d; d>>=1){ p0 += __shfl_xor(p0,d); p1 += __shfl_xor(p1,d); }
  if(lane==0){
    float d = dinv[node];
    float2 self = u[node];
    float z0 = d*(p0 + self.x) + b3[0];
    float z1 = d*(p1 + self.y) + b3[1];
    float m = fmaxf(z0,z1);
    float l = m + logf(expf(z0-m)+expf(z1-m));
    out[2*node]   = z0-l;
    out[2*node+1] = z1-l;
  }
}

extern "C" void kernel_launch(void* const* d_in, const int* in_sizes, int n_in,
                              void* d_out, int out_size, void* d_ws, size_t ws_size,
                              hipStream_t stream){
  const float* x  = (const float*)d_in[0];
  const int*   ei = (const int*)  d_in[1];
  const float* W1 = (const float*)d_in[2];
  const float* b1 = (const float*)d_in[3];
  const float* W2 = (const float*)d_in[4];
  const float* b2 = (const float*)d_in[5];
  const float* W3 = (const float*)d_in[6];
  const float* b3 = (const float*)d_in[7];
  float* out = (float*)d_out;

  const int n = in_sizes[0] / P;       // 50000
  const int e = in_sizes[1] / 2;       // 1600000
  const int* row = ei;
  const int* col = ei + e;
  const int nb = (n + BWID - 1) >> BW_LOG;

  float* ws   = (float*)d_ws;
  size_t off = 0;
  float* dinv = ws + off; off += n;
  float* R1   = ws + off; off += (size_t)64*n;
  float* R2   = ws + off; off += (size_t)128*n;
  int* rowptr = (int*)(ws + off); off += n+1;
  int* srcA   = (int*)(ws + off); off += e;
  int* bcnt   = (int*)(ws + off); off += NBMAX;
  int* bstart = (int*)(ws + off); off += NBMAX;
  int* bcursor= (int*)(ws + off); off += NBMAX;

  unsigned* pairs = (unsigned*)R2;  // live only during CSR build

  float* u1  = R1;   // dinv.(x@W1)        (dead after pull-1)
  float* g1s = R2;   // dinv.relu(layer1)  (dead after pull-2)
  float* a2  = R1;   // layer-2 aggregate  (dead after gemm23)
  float* u3  = R2;   // dinv.(h2@W3), 2n   (dead after pull2_lsm)

  const int BT = 256;

  k_zero <<<(nb+BT-1)/BT, BT, 0, stream>>>(bcnt, nb);
  k_bhist<<<(e+2047)/2048, BT, 0, stream>>>(col, bcnt, e, nb);
  k_bscan<<<1, NBMAX, 0, stream>>>(bcnt, bstart, bcursor, nb);
  k_part <<<(e+T1-1)/T1, 1024, 0, stream>>>(row, col, bcursor, pairs, e, nb);
  k_csr  <<<nb, BT, 0, stream>>>(pairs, bstart, bcnt, srcA, rowptr, dinv, n, e);

  k_gemm1<<<(n+63)/64, BT, 0, stream>>>(x, W1, dinv, u1, n);
  k_pull64<1><<<(n+3)/4, BT, 0, stream>>>(srcA, rowptr, u1, dinv, b1, g1s, n);

  k_pull64<2><<<(n+3)/4, BT, 0, stream>>>(srcA, rowptr, g1s, dinv, nullptr, a2, n);
  k_gemm23<<<(n+63)/64, BT, 0, stream>>>(a2, W2, b2, W3, dinv, u3, n);

  k_pull2_lsm<<<(n+3)/4, BT, 0, stream>>>(srcA, rowptr, u3, dinv, b3, out, n);
}

// Round 8
// 243.853 us; speedup vs baseline: 4.2768x; 1.0003x over previous
//
#include <hip/hip_runtime.h>

constexpr int P  = 128;  // input features
constexpr int H  = 64;   // hidden 1
constexpr int H2 = 128;  // hidden 2
constexpr int C  = 2;    // classes

constexpr int BW_LOG = 7;        // bucket width = 128 destinations
constexpr int BWID   = 128;
constexpr int NBMAX  = 512;      // max buckets supported (n <= 65536)
constexpr int T1     = 8192;     // edges per partition block
constexpr int CAP2   = 15360;    // k_csr LDS staging capacity (ints)

// ---------------- CSR build (two-level LDS-staged partition) ----------------
__global__ void k_zero(int* __restrict__ p, int n){
  int i = blockIdx.x*blockDim.x + threadIdx.x;
  if(i<n) p[i]=0;
}

__global__ __launch_bounds__(256) void k_bhist(const int* __restrict__ col,
                                               int* __restrict__ bcnt, int e, int nb){
  __shared__ int h[NBMAX];
  for(int i=threadIdx.x;i<nb;i+=256) h[i]=0;
  __syncthreads();
  int b0 = blockIdx.x*2048;
  #pragma unroll
  for(int u=0;u<8;u++){
    int idx = b0 + u*256 + threadIdx.x;
    if(idx<e) atomicAdd(&h[col[idx]>>BW_LOG], 1);
  }
  __syncthreads();
  for(int i=threadIdx.x;i<nb;i+=256) if(h[i]) atomicAdd(&bcnt[i], h[i]);
}

__global__ __launch_bounds__(NBMAX) void k_bscan(const int* __restrict__ bcnt,
                                                 int* __restrict__ bstart,
                                                 int* __restrict__ bcursor, int nb){
  __shared__ int sm[NBMAX];
  int t = threadIdx.x;
  int v = (t<nb)? bcnt[t] : 0;
  sm[t]=v; __syncthreads();
  for(int d=1; d<NBMAX; d<<=1){
    int u = (t>=d)? sm[t-d] : 0;
    __syncthreads();
    sm[t]+=u;
    __syncthreads();
  }
  if(t<nb){ int s = sm[t]-v; bstart[t]=s; bcursor[t]=s; }
}

__global__ __launch_bounds__(1024) void k_part(const int* __restrict__ row,
                                               const int* __restrict__ col,
                                               int* __restrict__ bcursor,
                                               unsigned* __restrict__ pairs, int e, int nb){
  __shared__ unsigned stage[T1];
  __shared__ int hist[NBMAX];
  __shared__ int base[NBMAX];
  __shared__ int gpos[NBMAX];
  int tid = threadIdx.x;
  int e0 = blockIdx.x*T1;
  int cnt = min(T1, e-e0);
  for(int i=tid;i<nb;i+=1024) hist[i]=0;
  __syncthreads();
  int myb[8]; int myrank[8]; unsigned mypack[8];
  #pragma unroll
  for(int u=0;u<8;u++){
    int idx = u*1024 + tid;
    if(idx<cnt){
      int c = col[e0+idx], r = row[e0+idx];
      int b = c>>BW_LOG;
      myb[u] = b;
      mypack[u] = ((unsigned)r<<BW_LOG) | (unsigned)(c & (BWID-1));
      myrank[u] = atomicAdd(&hist[b], 1);
    } else myb[u] = -1;
  }
  __syncthreads();
  if(tid<NBMAX) base[tid] = (tid<nb)? hist[tid] : 0;
  __syncthreads();
  for(int d=1; d<NBMAX; d<<=1){
    int u2 = 0;
    if(tid<NBMAX && tid>=d) u2 = base[tid-d];
    __syncthreads();
    if(tid<NBMAX) base[tid] += u2;
    __syncthreads();
  }
  if(tid<nb){
    int ex = base[tid] - hist[tid];
    base[tid] = ex;
    gpos[tid] = atomicAdd(&bcursor[tid], hist[tid]);
  }
  __syncthreads();
  #pragma unroll
  for(int u=0;u<8;u++){
    if(myb[u]>=0) stage[ base[myb[u]] + myrank[u] ] = mypack[u];
  }
  __syncthreads();
  int wave = tid>>6, lane = tid&63;
  for(int b=wave; b<nb; b+=16){
    int len = hist[b], lo = base[b], go = gpos[b];
    for(int k=lane; k<len; k+=64) pairs[go+k] = stage[lo+k];
  }
}

__global__ __launch_bounds__(256) void k_csr(const unsigned* __restrict__ pairs,
                                             const int* __restrict__ bstart,
                                             const int* __restrict__ bcnt,
                                             int* __restrict__ srcA,
                                             int* __restrict__ rowptr,
                                             float* __restrict__ dinv,
                                             int n, int e){
  __shared__ int hist[BWID];
  __shared__ int base[BWID];
  __shared__ int cur[BWID];
  __shared__ int stageS[CAP2];
  int b = blockIdx.x, tid = threadIdx.x;
  int lo = bstart[b], cnt = bcnt[b];
  if(tid<BWID) hist[tid]=0;
  __syncthreads();
  for(int i=tid;i<cnt;i+=256) atomicAdd(&hist[pairs[lo+i] & (BWID-1)], 1);
  __syncthreads();
  if(tid<BWID) base[tid] = hist[tid];
  __syncthreads();
  for(int d=1; d<BWID; d<<=1){
    int u = 0;
    if(tid<BWID && tid>=d) u = base[tid-d];
    __syncthreads();
    if(tid<BWID) base[tid] += u;
    __syncthreads();
  }
  if(tid<BWID){
    int ex = base[tid] - hist[tid];
    base[tid] = ex;
    cur[tid] = ex;
    int node = (b<<BW_LOG) + tid;
    if(node<n){
      rowptr[node] = lo + ex;
      dinv[node]   = rsqrtf((float)hist[tid] + 1.0f);
    }
  }
  if(b==0 && tid==0) rowptr[n] = e;
  __syncthreads();
  if(cnt<=CAP2){
    for(int i=tid;i<cnt;i+=256){
      unsigned p = pairs[lo+i];
      int pos = atomicAdd(&cur[p & (BWID-1)], 1);
      stageS[pos] = (int)(p>>BW_LOG);
    }
    __syncthreads();
    for(int i=tid;i<cnt;i+=256) srcA[lo+i] = stageS[i];
  } else {
    for(int i=tid;i<cnt;i+=256){
      unsigned p = pairs[lo+i];
      int pos = atomicAdd(&cur[p & (BWID-1)], 1);
      srcA[lo+pos] = (int)(p>>BW_LOG);
    }
  }
}

// ---------------- GEMM1: tiled 64x64, k-split LDS staging ----------------
// u1 chunk-major: u1[ch][r][f16] = dinv[r]*sum_k x[r][k]*W1[k][16ch+f16]
__global__ __launch_bounds__(256) void k_gemm1(const float* __restrict__ x,
                                               const float* __restrict__ W,
                                               const float* __restrict__ dinv,
                                               float* __restrict__ out, int n){
  __shared__ float xs[64][68];
  __shared__ float ws[64][64];
  int tid = threadIdx.x;
  int tx = tid & 15, ty = tid >> 4;
  int r0 = blockIdx.x*64;
  float acc[4][4] = {};
  const float4* x4 = (const float4*)x;
  const float4* W4 = (const float4*)W;
  for(int kh=0; kh<2; ++kh){
    __syncthreads();
    #pragma unroll
    for(int it=0; it<4; ++it){
      int idx = tid + 256*it;
      int r = idx >> 4, k4 = idx & 15;
      int gr = r0 + r;
      float4 v = (gr<n) ? x4[(size_t)gr*32 + kh*16 + k4] : make_float4(0.f,0.f,0.f,0.f);
      *(float4*)&xs[r][4*k4] = v;
    }
    #pragma unroll
    for(int it=0; it<4; ++it){
      int idx = tid + 256*it;
      int kk = idx >> 4, c4 = idx & 15;
      *(float4*)&ws[kk][4*c4] = W4[(size_t)(kh*64+kk)*16 + c4];
    }
    __syncthreads();
    #pragma unroll 8
    for(int kk=0; kk<64; ++kk){
      float xv0 = xs[4*ty+0][kk];
      float xv1 = xs[4*ty+1][kk];
      float xv2 = xs[4*ty+2][kk];
      float xv3 = xs[4*ty+3][kk];
      float4 wv = *(const float4*)&ws[kk][4*tx];
      acc[0][0] += xv0*wv.x; acc[0][1] += xv0*wv.y; acc[0][2] += xv0*wv.z; acc[0][3] += xv0*wv.w;
      acc[1][0] += xv1*wv.x; acc[1][1] += xv1*wv.y; acc[1][2] += xv1*wv.z; acc[1][3] += xv1*wv.w;
      acc[2][0] += xv2*wv.x; acc[2][1] += xv2*wv.y; acc[2][2] += xv2*wv.z; acc[2][3] += xv2*wv.w;
      acc[3][0] += xv3*wv.x; acc[3][1] += xv3*wv.y; acc[3][2] += xv3*wv.z; acc[3][3] += xv3*wv.w;
    }
  }
  // chunk-major write: col 4*tx+i -> chunk tx>>2, in-chunk quad tx&3
  float* ob = out + (size_t)(tx>>2)*n*16 + 4*(tx&3);
  #pragma unroll
  for(int i=0;i<4;i++){
    int gr = r0 + 4*ty + i;
    if(gr<n){
      float d = dinv[gr];
      float4 o = make_float4(acc[i][0]*d, acc[i][1]*d, acc[i][2]*d, acc[i][3]*d);
      *(float4*)&ob[(size_t)gr*16] = o;
    }
  }
}

// ---------------- GEMM2+GEMM3 fused (a2 input is chunk-major [4][n][16]) ----------------
__global__ __launch_bounds__(256) void k_gemm23(const float* __restrict__ a2,
                                                const float* __restrict__ W2,
                                                const float* __restrict__ b2,
                                                const float* __restrict__ W3,
                                                const float* __restrict__ dinv,
                                                float* __restrict__ u3, int n){
  __shared__ float as[64][68];
  __shared__ float ws[64][128];
  __shared__ float w3s[H2*C];
  __shared__ float b2s[H2];
  int tid = threadIdx.x;
  int tx = tid & 15, ty = tid >> 4;
  int r0 = blockIdx.x*64;
  const float4* a4 = (const float4*)a2;   // [4][n][4] float4s
  const float4* W24 = (const float4*)W2;
  #pragma unroll
  for(int it=0; it<4; ++it){
    int idx = tid + 256*it;
    int r = idx >> 4, k4 = idx & 15;
    int gr = r0 + r;
    float4 v = (gr<n) ? a4[(size_t)(k4>>2)*n*4 + (size_t)gr*4 + (k4&3)] : make_float4(0.f,0.f,0.f,0.f);
    *(float4*)&as[r][4*k4] = v;
  }
  #pragma unroll
  for(int it=0; it<8; ++it){
    int idx = tid + 256*it;
    int kk = idx >> 5, c4 = idx & 31;
    *(float4*)&ws[kk][4*c4] = W24[(size_t)kk*32 + c4];
  }
  if(tid < H2*C) w3s[tid] = W3[tid];
  if(tid < H2)   b2s[tid] = b2[tid];
  __syncthreads();
  float acc[4][8] = {};
  #pragma unroll 4
  for(int kk=0; kk<64; ++kk){
    float xv0 = as[4*ty+0][kk];
    float xv1 = as[4*ty+1][kk];
    float xv2 = as[4*ty+2][kk];
    float xv3 = as[4*ty+3][kk];
    float4 wa = *(const float4*)&ws[kk][8*tx];
    float4 wb = *(const float4*)&ws[kk][8*tx+4];
    acc[0][0]+=xv0*wa.x; acc[0][1]+=xv0*wa.y; acc[0][2]+=xv0*wa.z; acc[0][3]+=xv0*wa.w;
    acc[0][4]+=xv0*wb.x; acc[0][5]+=xv0*wb.y; acc[0][6]+=xv0*wb.z; acc[0][7]+=xv0*wb.w;
    acc[1][0]+=xv1*wa.x; acc[1][1]+=xv1*wa.y; acc[1][2]+=xv1*wa.z; acc[1][3]+=xv1*wa.w;
    acc[1][4]+=xv1*wb.x; acc[1][5]+=xv1*wb.y; acc[1][6]+=xv1*wb.z; acc[1][7]+=xv1*wb.w;
    acc[2][0]+=xv2*wa.x; acc[2][1]+=xv2*wa.y; acc[2][2]+=xv2*wa.z; acc[2][3]+=xv2*wa.w;
    acc[2][4]+=xv2*wb.x; acc[2][5]+=xv2*wb.y; acc[2][6]+=xv2*wb.z; acc[2][7]+=xv2*wb.w;
    acc[3][0]+=xv3*wa.x; acc[3][1]+=xv3*wa.y; acc[3][2]+=xv3*wa.z; acc[3][3]+=xv3*wa.w;
    acc[3][4]+=xv3*wb.x; acc[3][5]+=xv3*wb.y; acc[3][6]+=xv3*wb.z; acc[3][7]+=xv3*wb.w;
  }
  float p[4][2] = {};
  #pragma unroll
  for(int j=0;j<8;j++){
    int c = 8*tx + j;
    float w30 = w3s[2*c], w31 = w3s[2*c+1], bb = b2s[c];
    #pragma unroll
    for(int i=0;i<4;i++){
      float g = fmaxf(acc[i][j] + bb, 0.f);
      p[i][0] += g*w30;
      p[i][1] += g*w31;
    }
  }
  #pragma unroll
  for(int d=1; d<16; d<<=1){
    #pragma unroll
    for(int i=0;i<4;i++){
      p[i][0] += __shfl_xor(p[i][0], d);
      p[i][1] += __shfl_xor(p[i][1], d);
    }
  }
  if(tx==0){
    #pragma unroll
    for(int i=0;i<4;i++){
      int gr = r0 + 4*ty + i;
      if(gr<n){
        float d = dinv[gr];
        u3[2*gr]   = d*p[i][0];
        u3[2*gr+1] = d*p[i][1];
      }
    }
  }
}

// ---------------- chunked pull: wave per (node, chunk), 16 edge-slots x 4 lanes ----------------
// tc/outc chunk-major [4][n][16]; chunk = blockIdx.x & 3 (XCD-affine, 3.2MB L2-resident).
// MODE 1: out = dinv*relu(dinv*sum + bias)   MODE 2: out = dinv*sum
template<int MODE>
__global__ __launch_bounds__(256) void k_pull64c(const int* __restrict__ src,
                                                 const int* __restrict__ rowptr,
                                                 const float* __restrict__ tc,
                                                 const float* __restrict__ dinv,
                                                 const float* __restrict__ bias,
                                                 float* __restrict__ outc, int n){
  int chunk = blockIdx.x & 3;
  int node  = (blockIdx.x >> 2)*4 + (threadIdx.x>>6);
  if(node>=n) return;
  int lane = threadIdx.x & 63;
  int slot = lane >> 2;     // edge slot 0..15
  int q    = lane & 3;      // feature quad within chunk
  const float4* t4 = (const float4*)(tc + (size_t)chunk*n*16);
  float4 a0 = make_float4(0.f,0.f,0.f,0.f), a1 = a0;
  int beg = rowptr[node], end = rowptr[node+1];
  int j = beg;
  for(; j+32<=end; j+=32){
    int s0 = src[j+slot], s1 = src[j+16+slot];
    float4 v0 = t4[(size_t)s0*4+q];
    float4 v1 = t4[(size_t)s1*4+q];
    a0.x+=v0.x; a0.y+=v0.y; a0.z+=v0.z; a0.w+=v0.w;
    a1.x+=v1.x; a1.y+=v1.y; a1.z+=v1.z; a1.w+=v1.w;
  }
  for(; j+16<=end; j+=16){
    int s = src[j+slot];
    float4 v = t4[(size_t)s*4+q];
    a0.x+=v.x; a0.y+=v.y; a0.z+=v.z; a0.w+=v.w;
  }
  if(j+slot<end){
    int s = src[j+slot];
    float4 v = t4[(size_t)s*4+q];
    a0.x+=v.x; a0.y+=v.y; a0.z+=v.z; a0.w+=v.w;
  }
  a0.x+=a1.x; a0.y+=a1.y; a0.z+=a1.z; a0.w+=a1.w;
  // reduce over slot bits (lane bits 2..5)
  #pragma unroll
  for(int d=4; d<64; d<<=1){
    a0.x += __shfl_xor(a0.x,d);
    a0.y += __shfl_xor(a0.y,d);
    a0.z += __shfl_xor(a0.z,d);
    a0.w += __shfl_xor(a0.w,d);
  }
  if(slot==0){
    float4 self = t4[(size_t)node*4+q];
    float d = dinv[node];
    float4 o;
    if(MODE==1){
      float4 bq = ((const float4*)bias)[chunk*4+q];
      o.x = d*fmaxf(d*(a0.x+self.x) + bq.x, 0.f);
      o.y = d*fmaxf(d*(a0.y+self.y) + bq.y, 0.f);
      o.z = d*fmaxf(d*(a0.z+self.z) + bq.z, 0.f);
      o.w = d*fmaxf(d*(a0.w+self.w) + bq.w, 0.f);
    } else {
      o.x = d*(a0.x+self.x);
      o.y = d*(a0.y+self.y);
      o.z = d*(a0.z+self.z);
      o.w = d*(a0.w+self.w);
    }
    ((float4*)(outc + (size_t)chunk*n*16))[(size_t)node*4+q] = o;
  }
}

// F=2 pull + bias + log_softmax fused
__global__ __launch_bounds__(256) void k_pull2_lsm(const int* __restrict__ src,
                                                   const int* __restrict__ rowptr,
                                                   const float* __restrict__ u3,
                                                   const float* __restrict__ dinv,
                                                   const float* __restrict__ b3,
                                                   float* __restrict__ out, int n){
  int node = blockIdx.x*4 + (threadIdx.x>>6);
  int lane = threadIdx.x & 63;
  if(node>=n) return;
  const float2* u = (const float2*)u3;
  int beg = rowptr[node], end = rowptr[node+1];
  float p0=0.f, p1=0.f, q0=0.f, q1=0.f;
  int j = beg + lane;
  for(; j+64 < end; j += 128){
    float2 A = u[src[j]];
    float2 B = u[src[j+64]];
    p0 += A.x; p1 += A.y; q0 += B.x; q1 += B.y;
  }
  if(j < end){ float2 A = u[src[j]]; p0 += A.x; p1 += A.y; }
  p0 += q0; p1 += q1;
  #pragma unroll
  for(int d=32; d; d>>=1){ p0 += __shfl_xor(p0,d); p1 += __shfl_xor(p1,d); }
  if(lane==0){
    float d = dinv[node];
    float2 self = u[node];
    float z0 = d*(p0 + self.x) + b3[0];
    float z1 = d*(p1 + self.y) + b3[1];
    float m = fmaxf(z0,z1);
    float l = m + logf(expf(z0-m)+expf(z1-m));
    out[2*node]   = z0-l;
    out[2*node+1] = z1-l;
  }
}

extern "C" void kernel_launch(void* const* d_in, const int* in_sizes, int n_in,
                              void* d_out, int out_size, void* d_ws, size_t ws_size,
                              hipStream_t stream){
  const float* x  = (const float*)d_in[0];
  const int*   ei = (const int*)  d_in[1];
  const float* W1 = (const float*)d_in[2];
  const float* b1 = (const float*)d_in[3];
  const float* W2 = (const float*)d_in[4];
  const float* b2 = (const float*)d_in[5];
  const float* W3 = (const float*)d_in[6];
  const float* b3 = (const float*)d_in[7];
  float* out = (float*)d_out;

  const int n = in_sizes[0] / P;       // 50000
  const int e = in_sizes[1] / 2;       // 1600000
  const int* row = ei;
  const int* col = ei + e;
  const int nb = (n + BWID - 1) >> BW_LOG;

  float* ws   = (float*)d_ws;
  size_t off = 0;
  float* dinv = ws + off; off += n;
  float* R1   = ws + off; off += (size_t)64*n;
  float* R2   = ws + off; off += (size_t)128*n;
  int* rowptr = (int*)(ws + off); off += n+1;
  int* srcA   = (int*)(ws + off); off += e;
  int* bcnt   = (int*)(ws + off); off += NBMAX;
  int* bstart = (int*)(ws + off); off += NBMAX;
  int* bcursor= (int*)(ws + off); off += NBMAX;

  unsigned* pairs = (unsigned*)R2;  // live only during CSR build

  float* u1  = R1;   // chunk-major dinv.(x@W1)       (dead after pull-1)
  float* g1s = R2;   // chunk-major dinv.relu(L1)     (dead after pull-2)
  float* a2  = R1;   // chunk-major L2 aggregate      (dead after gemm23)
  float* u3  = R2;   // row-major dinv.(h2@W3), 2n    (dead after pull2_lsm)

  const int BT = 256;

  k_zero <<<(nb+BT-1)/BT, BT, 0, stream>>>(bcnt, nb);
  k_bhist<<<(e+2047)/2048, BT, 0, stream>>>(col, bcnt, e, nb);
  k_bscan<<<1, NBMAX, 0, stream>>>(bcnt, bstart, bcursor, nb);
  k_part <<<(e+T1-1)/T1, 1024, 0, stream>>>(row, col, bcursor, pairs, e, nb);
  k_csr  <<<nb, BT, 0, stream>>>(pairs, bstart, bcnt, srcA, rowptr, dinv, n, e);

  k_gemm1<<<(n+63)/64, BT, 0, stream>>>(x, W1, dinv, u1, n);

  const int pgrid = ((n+3)/4)*4;   // (node-block, chunk) pairs; chunk = bid&3
  k_pull64c<1><<<pgrid, BT, 0, stream>>>(srcA, rowptr, u1, dinv, b1, g1s, n);
  k_pull64c<2><<<pgrid, BT, 0, stream>>>(srcA, rowptr, g1s, dinv, nullptr, a2, n);

  k_gemm23<<<(n+63)/64, BT, 0, stream>>>(a2, W2, b2, W3, dinv, u3, n);
  k_pull2_lsm<<<(n+3)/4, BT, 0, stream>>>(srcA, rowptr, u3, dinv, b3, out, n);
}

// Round 9
// 196.677 us; speedup vs baseline: 5.3027x; 1.2399x over previous
//
#include <hip/hip_runtime.h>
#include <hip/hip_fp16.h>

constexpr int P  = 128;  // input features
constexpr int H  = 64;   // hidden 1
constexpr int H2 = 128;  // hidden 2
constexpr int C  = 2;    // classes

constexpr int BW_LOG = 7;        // bucket width = 128 destinations
constexpr int BWID   = 128;
constexpr int NBMAX  = 512;      // max buckets supported (n <= 65536)
constexpr int T1     = 8192;     // edges per partition block
constexpr int CAP2   = 15360;    // k_csr LDS staging capacity (ints)

__device__ __forceinline__ float h_lo(unsigned u){
  return __half2float(__ushort_as_half((unsigned short)(u & 0xffffu)));
}
__device__ __forceinline__ float h_hi(unsigned u){
  return __half2float(__ushort_as_half((unsigned short)(u >> 16)));
}
__device__ __forceinline__ unsigned packh2(float a, float b){
  unsigned short la = __half_as_ushort(__float2half_rn(a));
  unsigned short lb = __half_as_ushort(__float2half_rn(b));
  return (unsigned)la | ((unsigned)lb << 16);
}

// ---------------- CSR build (two-level LDS-staged partition) ----------------
__global__ void k_zero(int* __restrict__ p, int n){
  int i = blockIdx.x*blockDim.x + threadIdx.x;
  if(i<n) p[i]=0;
}

__global__ __launch_bounds__(256) void k_bhist(const int* __restrict__ col,
                                               int* __restrict__ bcnt, int e, int nb){
  __shared__ int h[NBMAX];
  for(int i=threadIdx.x;i<nb;i+=256) h[i]=0;
  __syncthreads();
  int b0 = blockIdx.x*2048;
  #pragma unroll
  for(int u=0;u<8;u++){
    int idx = b0 + u*256 + threadIdx.x;
    if(idx<e) atomicAdd(&h[col[idx]>>BW_LOG], 1);
  }
  __syncthreads();
  for(int i=threadIdx.x;i<nb;i+=256) if(h[i]) atomicAdd(&bcnt[i], h[i]);
}

__global__ __launch_bounds__(NBMAX) void k_bscan(const int* __restrict__ bcnt,
                                                 int* __restrict__ bstart,
                                                 int* __restrict__ bcursor, int nb){
  __shared__ int sm[NBMAX];
  int t = threadIdx.x;
  int v = (t<nb)? bcnt[t] : 0;
  sm[t]=v; __syncthreads();
  for(int d=1; d<NBMAX; d<<=1){
    int u = (t>=d)? sm[t-d] : 0;
    __syncthreads();
    sm[t]+=u;
    __syncthreads();
  }
  if(t<nb){ int s = sm[t]-v; bstart[t]=s; bcursor[t]=s; }
}

__global__ __launch_bounds__(1024) void k_part(const int* __restrict__ row,
                                               const int* __restrict__ col,
                                               int* __restrict__ bcursor,
                                               unsigned* __restrict__ pairs, int e, int nb){
  __shared__ unsigned stage[T1];
  __shared__ int hist[NBMAX];
  __shared__ int base[NBMAX];
  __shared__ int gpos[NBMAX];
  int tid = threadIdx.x;
  int e0 = blockIdx.x*T1;
  int cnt = min(T1, e-e0);
  for(int i=tid;i<nb;i+=1024) hist[i]=0;
  __syncthreads();
  int myb[8]; int myrank[8]; unsigned mypack[8];
  #pragma unroll
  for(int u=0;u<8;u++){
    int idx = u*1024 + tid;
    if(idx<cnt){
      int c = col[e0+idx], r = row[e0+idx];
      int b = c>>BW_LOG;
      myb[u] = b;
      mypack[u] = ((unsigned)r<<BW_LOG) | (unsigned)(c & (BWID-1));
      myrank[u] = atomicAdd(&hist[b], 1);
    } else myb[u] = -1;
  }
  __syncthreads();
  if(tid<NBMAX) base[tid] = (tid<nb)? hist[tid] : 0;
  __syncthreads();
  for(int d=1; d<NBMAX; d<<=1){
    int u2 = 0;
    if(tid<NBMAX && tid>=d) u2 = base[tid-d];
    __syncthreads();
    if(tid<NBMAX) base[tid] += u2;
    __syncthreads();
  }
  if(tid<nb){
    int ex = base[tid] - hist[tid];
    base[tid] = ex;
    gpos[tid] = atomicAdd(&bcursor[tid], hist[tid]);
  }
  __syncthreads();
  #pragma unroll
  for(int u=0;u<8;u++){
    if(myb[u]>=0) stage[ base[myb[u]] + myrank[u] ] = mypack[u];
  }
  __syncthreads();
  int wave = tid>>6, lane = tid&63;
  for(int b=wave; b<nb; b+=16){
    int len = hist[b], lo = base[b], go = gpos[b];
    for(int k=lane; k<len; k+=64) pairs[go+k] = stage[lo+k];
  }
}

__global__ __launch_bounds__(256) void k_csr(const unsigned* __restrict__ pairs,
                                             const int* __restrict__ bstart,
                                             const int* __restrict__ bcnt,
                                             int* __restrict__ srcA,
                                             int* __restrict__ rowptr,
                                             float* __restrict__ dinv,
                                             int n, int e){
  __shared__ int hist[BWID];
  __shared__ int base[BWID];
  __shared__ int cur[BWID];
  __shared__ int stageS[CAP2];
  int b = blockIdx.x, tid = threadIdx.x;
  int lo = bstart[b], cnt = bcnt[b];
  if(tid<BWID) hist[tid]=0;
  __syncthreads();
  for(int i=tid;i<cnt;i+=256) atomicAdd(&hist[pairs[lo+i] & (BWID-1)], 1);
  __syncthreads();
  if(tid<BWID) base[tid] = hist[tid];
  __syncthreads();
  for(int d=1; d<BWID; d<<=1){
    int u = 0;
    if(tid<BWID && tid>=d) u = base[tid-d];
    __syncthreads();
    if(tid<BWID) base[tid] += u;
    __syncthreads();
  }
  if(tid<BWID){
    int ex = base[tid] - hist[tid];
    base[tid] = ex;
    cur[tid] = ex;
    int node = (b<<BW_LOG) + tid;
    if(node<n){
      rowptr[node] = lo + ex;
      dinv[node]   = rsqrtf((float)hist[tid] + 1.0f);
    }
  }
  if(b==0 && tid==0) rowptr[n] = e;
  __syncthreads();
  if(cnt<=CAP2){
    for(int i=tid;i<cnt;i+=256){
      unsigned p = pairs[lo+i];
      int pos = atomicAdd(&cur[p & (BWID-1)], 1);
      stageS[pos] = (int)(p>>BW_LOG);
    }
    __syncthreads();
    for(int i=tid;i<cnt;i+=256) srcA[lo+i] = stageS[i];
  } else {
    for(int i=tid;i<cnt;i+=256){
      unsigned p = pairs[lo+i];
      int pos = atomicAdd(&cur[p & (BWID-1)], 1);
      srcA[lo+pos] = (int)(p>>BW_LOG);
    }
  }
}

// ---------------- GEMM1: tiled 64x64 -> fp16 chunk-major out [2][n][32] ----------------
__global__ __launch_bounds__(256) void k_gemm1(const float* __restrict__ x,
                                               const float* __restrict__ W,
                                               const float* __restrict__ dinv,
                                               unsigned* __restrict__ out, int n){
  __shared__ float xs[64][68];
  __shared__ float ws[64][64];
  int tid = threadIdx.x;
  int tx = tid & 15, ty = tid >> 4;
  int r0 = blockIdx.x*64;
  float acc[4][4] = {};
  const float4* x4 = (const float4*)x;
  const float4* W4 = (const float4*)W;
  for(int kh=0; kh<2; ++kh){
    __syncthreads();
    #pragma unroll
    for(int it=0; it<4; ++it){
      int idx = tid + 256*it;
      int r = idx >> 4, k4 = idx & 15;
      int gr = r0 + r;
      float4 v = (gr<n) ? x4[(size_t)gr*32 + kh*16 + k4] : make_float4(0.f,0.f,0.f,0.f);
      *(float4*)&xs[r][4*k4] = v;
    }
    #pragma unroll
    for(int it=0; it<4; ++it){
      int idx = tid + 256*it;
      int kk = idx >> 4, c4 = idx & 15;
      *(float4*)&ws[kk][4*c4] = W4[(size_t)(kh*64+kk)*16 + c4];
    }
    __syncthreads();
    #pragma unroll 8
    for(int kk=0; kk<64; ++kk){
      float xv0 = xs[4*ty+0][kk];
      float xv1 = xs[4*ty+1][kk];
      float xv2 = xs[4*ty+2][kk];
      float xv3 = xs[4*ty+3][kk];
      float4 wv = *(const float4*)&ws[kk][4*tx];
      acc[0][0] += xv0*wv.x; acc[0][1] += xv0*wv.y; acc[0][2] += xv0*wv.z; acc[0][3] += xv0*wv.w;
      acc[1][0] += xv1*wv.x; acc[1][1] += xv1*wv.y; acc[1][2] += xv1*wv.z; acc[1][3] += xv1*wv.w;
      acc[2][0] += xv2*wv.x; acc[2][1] += xv2*wv.y; acc[2][2] += xv2*wv.z; acc[2][3] += xv2*wv.w;
      acc[3][0] += xv3*wv.x; acc[3][1] += xv3*wv.y; acc[3][2] += xv3*wv.z; acc[3][3] += xv3*wv.w;
    }
  }
  // fp16 chunk-major write: cols 4tx..4tx+3 -> chunk tx>>3, row = 16 uints
  unsigned* ob = out + (size_t)(tx>>3)*n*16 + 2*(tx&7);
  #pragma unroll
  for(int i=0;i<4;i++){
    int gr = r0 + 4*ty + i;
    if(gr<n){
      float d = dinv[gr];
      uint2 w;
      w.x = packh2(acc[i][0]*d, acc[i][1]*d);
      w.y = packh2(acc[i][2]*d, acc[i][3]*d);
      *(uint2*)&ob[(size_t)gr*16] = w;
    }
  }
}

// ---------------- GEMM2+GEMM3 fused (a2 row-major f32 [n][64]) ----------------
__global__ __launch_bounds__(256) void k_gemm23(const float* __restrict__ a2,
                                                const float* __restrict__ W2,
                                                const float* __restrict__ b2,
                                                const float* __restrict__ W3,
                                                const float* __restrict__ dinv,
                                                float* __restrict__ u3, int n){
  __shared__ float as[64][68];
  __shared__ float ws[64][128];
  __shared__ float w3s[H2*C];
  __shared__ float b2s[H2];
  int tid = threadIdx.x;
  int tx = tid & 15, ty = tid >> 4;
  int r0 = blockIdx.x*64;
  const float4* a4 = (const float4*)a2;
  const float4* W24 = (const float4*)W2;
  #pragma unroll
  for(int it=0; it<4; ++it){
    int idx = tid + 256*it;
    int r = idx >> 4, k4 = idx & 15;
    int gr = r0 + r;
    float4 v = (gr<n) ? a4[(size_t)gr*16 + k4] : make_float4(0.f,0.f,0.f,0.f);
    *(float4*)&as[r][4*k4] = v;
  }
  #pragma unroll
  for(int it=0; it<8; ++it){
    int idx = tid + 256*it;
    int kk = idx >> 5, c4 = idx & 31;
    *(float4*)&ws[kk][4*c4] = W24[(size_t)kk*32 + c4];
  }
  if(tid < H2*C) w3s[tid] = W3[tid];
  if(tid < H2)   b2s[tid] = b2[tid];
  __syncthreads();
  float acc[4][8] = {};
  #pragma unroll 4
  for(int kk=0; kk<64; ++kk){
    float xv0 = as[4*ty+0][kk];
    float xv1 = as[4*ty+1][kk];
    float xv2 = as[4*ty+2][kk];
    float xv3 = as[4*ty+3][kk];
    float4 wa = *(const float4*)&ws[kk][8*tx];
    float4 wb = *(const float4*)&ws[kk][8*tx+4];
    acc[0][0]+=xv0*wa.x; acc[0][1]+=xv0*wa.y; acc[0][2]+=xv0*wa.z; acc[0][3]+=xv0*wa.w;
    acc[0][4]+=xv0*wb.x; acc[0][5]+=xv0*wb.y; acc[0][6]+=xv0*wb.z; acc[0][7]+=xv0*wb.w;
    acc[1][0]+=xv1*wa.x; acc[1][1]+=xv1*wa.y; acc[1][2]+=xv1*wa.z; acc[1][3]+=xv1*wa.w;
    acc[1][4]+=xv1*wb.x; acc[1][5]+=xv1*wb.y; acc[1][6]+=xv1*wb.z; acc[1][7]+=xv1*wb.w;
    acc[2][0]+=xv2*wa.x; acc[2][1]+=xv2*wa.y; acc[2][2]+=xv2*wa.z; acc[2][3]+=xv2*wa.w;
    acc[2][4]+=xv2*wb.x; acc[2][5]+=xv2*wb.y; acc[2][6]+=xv2*wb.z; acc[2][7]+=xv2*wb.w;
    acc[3][0]+=xv3*wa.x; acc[3][1]+=xv3*wa.y; acc[3][2]+=xv3*wa.z; acc[3][3]+=xv3*wa.w;
    acc[3][4]+=xv3*wb.x; acc[3][5]+=xv3*wb.y; acc[3][6]+=xv3*wb.z; acc[3][7]+=xv3*wb.w;
  }
  float p[4][2] = {};
  #pragma unroll
  for(int j=0;j<8;j++){
    int c = 8*tx + j;
    float w30 = w3s[2*c], w31 = w3s[2*c+1], bb = b2s[c];
    #pragma unroll
    for(int i=0;i<4;i++){
      float g = fmaxf(acc[i][j] + bb, 0.f);
      p[i][0] += g*w30;
      p[i][1] += g*w31;
    }
  }
  #pragma unroll
  for(int d=1; d<16; d<<=1){
    #pragma unroll
    for(int i=0;i<4;i++){
      p[i][0] += __shfl_xor(p[i][0], d);
      p[i][1] += __shfl_xor(p[i][1], d);
    }
  }
  if(tx==0){
    #pragma unroll
    for(int i=0;i<4;i++){
      int gr = r0 + 4*ty + i;
      if(gr<n){
        float d = dinv[gr];
        u3[2*gr]   = d*p[i][0];
        u3[2*gr+1] = d*p[i][1];
      }
    }
  }
}

// ---------------- fp16 chunked pull: wave per (node, chunk=32 feats) ----------------
// table: fp16 chunk-major [2][n][32] (row = 64B). 16 edge-slots x 4 lanes x 16B.
// MODE 1: g1s(fp16 cm) = dinv*relu(dinv*sum + bias)   MODE 2: a2(f32 rm) = dinv*sum
template<int MODE>
__global__ __launch_bounds__(256) void k_pullh(const int* __restrict__ src,
                                               const int* __restrict__ rowptr,
                                               const uint4* __restrict__ th,
                                               const float* __restrict__ dinv,
                                               const float* __restrict__ bias,
                                               void* __restrict__ outp, int n){
  int chunk = blockIdx.x & 1;
  int node  = (blockIdx.x >> 1)*4 + (threadIdx.x>>6);
  if(node>=n) return;
  int lane = threadIdx.x & 63;
  int slot = lane >> 2;     // edge slot 0..15
  int q    = lane & 3;      // 16B quad within 64B row
  const uint4* t4 = th + (size_t)chunk*n*4;
  float a[8] = {0.f,0.f,0.f,0.f,0.f,0.f,0.f,0.f};
  int beg = rowptr[node], end = rowptr[node+1];
  int j = beg;
  for(; j+32<=end; j+=32){
    int s0 = src[j+slot], s1 = src[j+16+slot];
    uint4 r0 = t4[(size_t)s0*4+q];
    uint4 r1 = t4[(size_t)s1*4+q];
    a[0]+=h_lo(r0.x); a[1]+=h_hi(r0.x); a[2]+=h_lo(r0.y); a[3]+=h_hi(r0.y);
    a[4]+=h_lo(r0.z); a[5]+=h_hi(r0.z); a[6]+=h_lo(r0.w); a[7]+=h_hi(r0.w);
    a[0]+=h_lo(r1.x); a[1]+=h_hi(r1.x); a[2]+=h_lo(r1.y); a[3]+=h_hi(r1.y);
    a[4]+=h_lo(r1.z); a[5]+=h_hi(r1.z); a[6]+=h_lo(r1.w); a[7]+=h_hi(r1.w);
  }
  for(; j+16<=end; j+=16){
    int s = src[j+slot];
    uint4 r = t4[(size_t)s*4+q];
    a[0]+=h_lo(r.x); a[1]+=h_hi(r.x); a[2]+=h_lo(r.y); a[3]+=h_hi(r.y);
    a[4]+=h_lo(r.z); a[5]+=h_hi(r.z); a[6]+=h_lo(r.w); a[7]+=h_hi(r.w);
  }
  if(j+slot < end){
    int s = src[j+slot];
    uint4 r = t4[(size_t)s*4+q];
    a[0]+=h_lo(r.x); a[1]+=h_hi(r.x); a[2]+=h_lo(r.y); a[3]+=h_hi(r.y);
    a[4]+=h_lo(r.z); a[5]+=h_hi(r.z); a[6]+=h_lo(r.w); a[7]+=h_hi(r.w);
  }
  // reduce over slot bits (lane bits 2..5)
  #pragma unroll
  for(int d=4; d<64; d<<=1){
    #pragma unroll
    for(int i=0;i<8;i++) a[i] += __shfl_xor(a[i], d);
  }
  if(slot==0){
    uint4 sr = t4[(size_t)node*4+q];   // self-loop row
    a[0]+=h_lo(sr.x); a[1]+=h_hi(sr.x); a[2]+=h_lo(sr.y); a[3]+=h_hi(sr.y);
    a[4]+=h_lo(sr.z); a[5]+=h_hi(sr.z); a[6]+=h_lo(sr.w); a[7]+=h_hi(sr.w);
    float dv = dinv[node];
    if(MODE==1){
      const float* bq = bias + chunk*32 + 8*q;
      float o[8];
      #pragma unroll
      for(int i=0;i<8;i++) o[i] = dv * fmaxf(dv*a[i] + bq[i], 0.f);
      uint4 w;
      w.x = packh2(o[0],o[1]); w.y = packh2(o[2],o[3]);
      w.z = packh2(o[4],o[5]); w.w = packh2(o[6],o[7]);
      ((uint4*)outp)[(size_t)chunk*n*4 + (size_t)node*4 + q] = w;
    } else {
      float* orow = (float*)outp + (size_t)node*64 + chunk*32 + 8*q;
      *(float4*)orow     = make_float4(dv*a[0], dv*a[1], dv*a[2], dv*a[3]);
      *(float4*)(orow+4) = make_float4(dv*a[4], dv*a[5], dv*a[6], dv*a[7]);
    }
  }
}

// F=2 pull + bias + log_softmax fused
__global__ __launch_bounds__(256) void k_pull2_lsm(const int* __restrict__ src,
                                                   const int* __restrict__ rowptr,
                                                   const float* __restrict__ u3,
                                                   const float* __restrict__ dinv,
                                                   const float* __restrict__ b3,
                                                   float* __restrict__ out, int n){
  int node = blockIdx.x*4 + (threadIdx.x>>6);
  int lane = threadIdx.x & 63;
  if(node>=n) return;
  const float2* u = (const float2*)u3;
  int beg = rowptr[node], end = rowptr[node+1];
  float p0=0.f, p1=0.f, q0=0.f, q1=0.f;
  int j = beg + lane;
  for(; j+64 < end; j += 128){
    float2 A = u[src[j]];
    float2 B = u[src[j+64]];
    p0 += A.x; p1 += A.y; q0 += B.x; q1 += B.y;
  }
  if(j < end){ float2 A = u[src[j]]; p0 += A.x; p1 += A.y; }
  p0 += q0; p1 += q1;
  #pragma unroll
  for(int d=32; d; d>>=1){ p0 += __shfl_xor(p0,d); p1 += __shfl_xor(p1,d); }
  if(lane==0){
    float d = dinv[node];
    float2 self = u[node];
    float z0 = d*(p0 + self.x) + b3[0];
    float z1 = d*(p1 + self.y) + b3[1];
    float m = fmaxf(z0,z1);
    float l = m + logf(expf(z0-m)+expf(z1-m));
    out[2*node]   = z0-l;
    out[2*node+1] = z1-l;
  }
}

extern "C" void kernel_launch(void* const* d_in, const int* in_sizes, int n_in,
                              void* d_out, int out_size, void* d_ws, size_t ws_size,
                              hipStream_t stream){
  const float* x  = (const float*)d_in[0];
  const int*   ei = (const int*)  d_in[1];
  const float* W1 = (const float*)d_in[2];
  const float* b1 = (const float*)d_in[3];
  const float* W2 = (const float*)d_in[4];
  const float* b2 = (const float*)d_in[5];
  const float* W3 = (const float*)d_in[6];
  const float* b3 = (const float*)d_in[7];
  float* out = (float*)d_out;

  const int n = in_sizes[0] / P;       // 50000
  const int e = in_sizes[1] / 2;       // 1600000
  const int* row = ei;
  const int* col = ei + e;
  const int nb = (n + BWID - 1) >> BW_LOG;

  float* ws   = (float*)d_ws;
  size_t off = 0;
  float* dinv = ws + off; off += n;
  float* R1   = ws + off; off += (size_t)64*n;
  float* R2   = ws + off; off += (size_t)128*n;
  int* rowptr = (int*)(ws + off); off += n+1;
  int* srcA   = (int*)(ws + off); off += e;
  int* bcnt   = (int*)(ws + off); off += NBMAX;
  int* bstart = (int*)(ws + off); off += NBMAX;
  int* bcursor= (int*)(ws + off); off += NBMAX;

  unsigned* pairs = (unsigned*)R2;           // live only during CSR build

  unsigned* u1h = (unsigned*)R1;             // fp16 cm [2][n][32] = 32n f32-equiv (dead after pull-1)
  unsigned* g1h = (unsigned*)R2;             // fp16 cm [2][n][32] (dead after pull-2)
  float*    a2  = R2 + (size_t)32*n;         // f32 rm [n][64]     (dead after gemm23)
  float*    u3  = R1;                        // f32 [n][2]         (dead after pull2_lsm)

  const int BT = 256;

  k_zero <<<(nb+BT-1)/BT, BT, 0, stream>>>(bcnt, nb);
  k_bhist<<<(e+2047)/2048, BT, 0, stream>>>(col, bcnt, e, nb);
  k_bscan<<<1, NBMAX, 0, stream>>>(bcnt, bstart, bcursor, nb);
  k_part <<<(e+T1-1)/T1, 1024, 0, stream>>>(row, col, bcursor, pairs, e, nb);
  k_csr  <<<nb, BT, 0, stream>>>(pairs, bstart, bcnt, srcA, rowptr, dinv, n, e);

  k_gemm1<<<(n+63)/64, BT, 0, stream>>>(x, W1, dinv, u1h, n);

  const int pg = ((n+3)/4)*2;   // (node-block, chunk) pairs; chunk = bid&1
  k_pullh<1><<<pg, BT, 0, stream>>>(srcA, rowptr, (const uint4*)u1h, dinv, b1, (void*)g1h, n);
  k_pullh<2><<<pg, BT, 0, stream>>>(srcA, rowptr, (const uint4*)g1h, dinv, nullptr, (void*)a2, n);

  k_gemm23<<<(n+63)/64, BT, 0, stream>>>(a2, W2, b2, W3, dinv, u3, n);
  k_pull2_lsm<<<(n+3)/4, BT, 0, stream>>>(srcA, rowptr, u3, dinv, b3, out, n);
}